// Round 15
// baseline (692.913 us; speedup 1.0000x reference)
//
#include <hip/hip_runtime.h>

// NaryTreeLSTMCell: B=32, L=512, E=H=1024.  Outputs h_out, c_out (f32, 2x16384x1024).
//
// ROUND 15 = TAIL MEASUREMENT ROUND. GEMM plateaued at ~301-305us across ten
// schedule variants (r4-r13); total is 526-549 but the non-gemm ~245us has
// NEVER been directly measured (top-5 monopolized by gemm replays). This round
// runs the REAL pipeline with fused_final<REPS=4> and convert_bf16<REPS=8>
// (both pure functions -> repetition is bit-identical; asm memory clobber
// prevents load hoisting). Read-out: fused time from its top-5 row /4;
// convert from the dur_us delta. dur_us is sacrificial this round.

#define ROWS 16384
#define HID  1024
#define KDIM 1024
#define NCOLS 4096
#define BM 256
#define BN 256

typedef __attribute__((ext_vector_type(4))) int            i32x4;
typedef __attribute__((ext_vector_type(4))) float          f32x4;
typedef __attribute__((ext_vector_type(4))) unsigned short u16x4;
typedef __attribute__((ext_vector_type(8))) unsigned short u16x8;

__device__ __forceinline__ unsigned short f2bf(float f) {
  unsigned u = __float_as_uint(f);
  unsigned r = 0x7FFFu + ((u >> 16) & 1u);
  return (unsigned short)((u + r) >> 16);
}
__device__ __forceinline__ float bf2f(unsigned short v) {
  return __uint_as_float(((unsigned)v) << 16);
}
__device__ __forceinline__ float sigmoidf_(float x) {
  return 1.0f / (1.0f + __expf(-x));
}
__device__ __forceinline__ void gload16(const void* g, void* l) {
  __builtin_amdgcn_global_load_lds(
      (const __attribute__((address_space(1))) void*)g,
      (__attribute__((address_space(3))) void*)l, 16, 0, 0);
}
__device__ __forceinline__ void mfma_bf16(f32x4& acc, i32x4 a, i32x4 b) {
  asm volatile("v_mfma_f32_16x16x32_bf16 %0, %1, %2, %0"
               : "+v"(acc) : "v"(a), "v"(b));
}

// ---- weight packing: transposed bf16 panels [N=4096][K=1024] ----

__global__ void pack_wx(const float* __restrict__ Wioux, const float* __restrict__ Wfx,
                        unsigned short* __restrict__ Wxt) {
  __shared__ float t[32][33];
  const int n0 = blockIdx.x * 32, k0 = blockIdx.y * 32;
  const int tx = threadIdx.x, ty = threadIdx.y;
  const int n = n0 + tx, k = k0 + ty;
  float v = (n < 3072) ? Wioux[(size_t)k * 3072 + n]
                       : Wfx[(size_t)k * 1024 + (n - 3072)];
  t[ty][tx] = v;
  __syncthreads();
  Wxt[(size_t)(n0 + ty) * KDIM + (k0 + tx)] = f2bf(t[tx][ty]);
}

__global__ void pack_wh(const float* __restrict__ Wiouh, const float* __restrict__ Wfh,
                        unsigned short* __restrict__ Wht) {
  __shared__ float t[32][33];
  const int n0 = blockIdx.x * 32, k0 = blockIdx.y * 32;
  const int tx = threadIdx.x, ty = threadIdx.y;
  const int n = n0 + tx, k = k0 + ty;
  float v;
  if (n < 1024)      v = Wiouh[(size_t)k * 3072 + n];
  else if (n < 2048) v = Wiouh[3145728u + (size_t)k * 3072 + (n - 1024)];
  else if (n < 3072) { const int c = n - 2048;
    v = Wfh[(size_t)k * 1024 + c] + Wfh[1048576u + (size_t)k * 1024 + c]; }
  else { const int c = n - 3072;
    v = Wfh[2097152u + (size_t)k * 1024 + c] + Wfh[3145728u + (size_t)k * 1024 + c]; }
  t[ty][tx] = v;
  __syncthreads();
  Wht[(size_t)(n0 + ty) * KDIM + (k0 + tx)] = f2bf(t[tx][ty]);
}

__global__ void pack_bias(const float* __restrict__ b_iouh, const float* __restrict__ b_fh,
                          float* __restrict__ bh) {
  const int n = blockIdx.x * 1024 + threadIdx.x;
  float v;
  if (n < 1024)      v = b_iouh[n];
  else if (n < 2048) v = b_iouh[3072 + (n - 1024)];
  else if (n < 3072) { const int c = n - 2048; v = b_fh[c] + b_fh[1024 + c]; }
  else { const int c = n - 3072; v = b_fh[2048 + c] + b_fh[3072 + c]; }
  bh[n] = v;
}

template<int REPS>
__global__ void convert_bf16(const float* __restrict__ x, const float* __restrict__ h0,
                             unsigned short* __restrict__ xb, unsigned short* __restrict__ hb) {
  for (int rep = 0; rep < REPS; ++rep) {
    const size_t i = ((size_t)blockIdx.x * 256 + threadIdx.x) * 4;
    const float4 a = *(const float4*)&x[i];
    const float4 b = *(const float4*)&h0[i];
    u16x4 av = { f2bf(a.x), f2bf(a.y), f2bf(a.z), f2bf(a.w) };
    u16x4 bv = { f2bf(b.x), f2bf(b.y), f2bf(b.z), f2bf(b.w) };
    *(u16x4*)&xb[i] = av;
    *(u16x4*)&hb[i] = bv;
    asm volatile("" ::: "memory");   // prevent cross-rep collapse
  }
}

// stage8: one gload16 per wave = 8 rows x 64B. Global seg pre-swizzled ^(row&7);
// LDS stays linear (global_load_lds constraint). rowbase multiple of 8.
__device__ __forceinline__ void stage8(const unsigned short* __restrict__ gp,
                                       unsigned short* __restrict__ lp,
                                       int rowbase, int gbase, int k0, int lane) {
  const int lrow = rowbase + (lane >> 3);
  const int sseg = (lane & 7) ^ ((lane >> 3) & 7);
  gload16(gp + (size_t)(gbase + lrow) * KDIM + k0 + sseg * 8,
          lp + ((size_t)rowbase << 6));
}

#define RD_A(dst, qm)                                                          \
  _Pragma("unroll")                                                            \
  for (int i = 0; i < 4; ++i) {                                                \
    const int row = wr * 128 + (qm) * 64 + i * 16 + m0;                        \
    _Pragma("unroll")                                                          \
    for (int s = 0; s < 2; ++s)                                                \
      dst[i][s] = *(const i32x4*)(Ab + row * 64 + (((kg + s * 4) ^ sw8) << 3)); \
  }

#define RD_B(dst, qn)                                                          \
  _Pragma("unroll")                                                            \
  for (int j = 0; j < 2; ++j) {                                                \
    const int col = wc * 64 + (qn) * 32 + j * 16 + m0;                         \
    _Pragma("unroll")                                                          \
    for (int s = 0; s < 2; ++s)                                                \
      dst[j][s] = *(const i32x4*)(Bb + col * 64 + (((kg + s * 4) ^ sw8) << 3)); \
  }

#define MM(afx, qmb, qnb)                                                      \
  __builtin_amdgcn_s_setprio(1);                                               \
  _Pragma("unroll")                                                            \
  for (int i = 0; i < 4; ++i)                                                  \
    _Pragma("unroll")                                                          \
    for (int j = 0; j < 2; ++j) {                                              \
      mfma_bf16(acc[(qmb) + i][(qnb) + j], afx[i][0], bfr[j][0]);              \
      mfma_bf16(acc[(qmb) + i][(qnb) + j], afx[i][1], bfr[j][1]);              \
    }                                                                          \
  __builtin_amdgcn_s_setprio(0);

__global__ __launch_bounds__(512, 2)
void gemm8(const unsigned short* __restrict__ xb, const unsigned short* __restrict__ hb,
           const unsigned short* __restrict__ Wxt, const unsigned short* __restrict__ Wht,
           unsigned short* __restrict__ gxb, unsigned short* __restrict__ ghb,
           const float* __restrict__ bhv) {
  __shared__ __align__(16) unsigned short S[2][2][256][64];  // [buf][A|B][row][64]

  const unsigned short* A;
  const unsigned short* Bt;
  unsigned short* Cp;
  const float* bias;
  if (blockIdx.z == 0) { A = xb; Bt = Wxt; Cp = gxb; bias = nullptr; }
  else                 { A = hb; Bt = Wht; Cp = ghb; bias = bhv; }

  // T1 XCD-aware swizzle (bijective; ny multiple of 8), y-major within chunk.
  int bx = blockIdx.x, by = blockIdx.y;
  const int ny = gridDim.y;
  if ((ny & 7) == 0) {
    const int n = blockIdx.x + 16 * blockIdx.y;
    const int xcd = n & 7, idx = n >> 3;
    const int ych = ny >> 3;
    bx = idx / ych;
    by = xcd * ych + (idx % ych);
  }
  const int bm = by * BM, bn = bx * BN;

  const int tid = threadIdx.x, w = tid >> 6, lane = tid & 63;
  const int wr = w >> 2, wc = w & 3;
  const int m0 = lane & 15, kg = lane >> 4, sw8 = m0 & 7;
  const int bq0 = ((w >> 1) << 6) + ((w & 1) << 4);

  f32x4 acc[8][4] = {};

  // prologue: stage all of tile 0 into buf 0, drain once
  stage8(A,  &S[0][0][0][0], w * 8,        bm, 0, lane);
  stage8(A,  &S[0][0][0][0], 128 + w * 8,  bm, 0, lane);
  stage8(A,  &S[0][0][0][0], 64 + w * 8,   bm, 0, lane);
  stage8(A,  &S[0][0][0][0], 192 + w * 8,  bm, 0, lane);
  stage8(Bt, &S[0][1][0][0], bq0,          bn, 0, lane);
  stage8(Bt, &S[0][1][0][0], bq0 + 8,      bn, 0, lane);
  stage8(Bt, &S[0][1][0][0], bq0 + 32,     bn, 0, lane);
  stage8(Bt, &S[0][1][0][0], bq0 + 40,     bn, 0, lane);
  asm volatile("s_waitcnt vmcnt(0)" ::: "memory");
  __builtin_amdgcn_s_barrier();

  for (int t = 0; t < 16; ++t) {
    const int cur = t & 1, nxt = cur ^ 1;
    const unsigned short* Ab = &S[cur][0][0][0];
    const unsigned short* Bb = &S[cur][1][0][0];
    unsigned short* An = &S[nxt][0][0][0];
    unsigned short* Bn = &S[nxt][1][0][0];
    const int k1 = (t + 1) << 6;
    const bool st = (t < 15);
    i32x4 af0[4][2], af1[4][2], bfr[2][2];

    // ---- P0 (qm0,qn0): rd af0+bfr0; stage A0(t+1); retire A1(t) ----
    RD_A(af0, 0)
    RD_B(bfr, 0)
    if (st) { stage8(A, An, w * 8, bm, k1, lane);
              stage8(A, An, 128 + w * 8, bm, k1, lane);
              asm volatile("s_waitcnt vmcnt(4)" ::: "memory"); }
    else    { asm volatile("s_waitcnt vmcnt(2)" ::: "memory"); }
    __builtin_amdgcn_s_barrier();
    MM(af0, 0, 0)
    __builtin_amdgcn_s_barrier();

    // ---- P1 (qm1,qn0): rd af1; stage B0(t+1); retire B1(t) ----
    RD_A(af1, 1)
    if (st) { stage8(Bt, Bn, bq0, bn, k1, lane);
              stage8(Bt, Bn, bq0 + 8, bn, k1, lane);
              asm volatile("s_waitcnt vmcnt(4)" ::: "memory"); }
    else    { asm volatile("s_waitcnt vmcnt(0)" ::: "memory"); }
    __builtin_amdgcn_s_barrier();
    MM(af1, 4, 0)
    __builtin_amdgcn_s_barrier();

    // ---- P2 (qm1,qn1): rd bfr1; stage A1(t+1); no wait ----
    RD_B(bfr, 1)
    if (st) { stage8(A, An, 64 + w * 8, bm, k1, lane);
              stage8(A, An, 192 + w * 8, bm, k1, lane); }
    __builtin_amdgcn_s_barrier();
    MM(af1, 4, 2)
    __builtin_amdgcn_s_barrier();

    // ---- P3 (qm0,qn1): no reads; stage B1(t+1); retire A0/B0(t+1) ----
    if (st) { stage8(Bt, Bn, bq0 + 32, bn, k1, lane);
              stage8(Bt, Bn, bq0 + 40, bn, k1, lane);
              asm volatile("s_waitcnt vmcnt(4)" ::: "memory"); }
    __builtin_amdgcn_s_barrier();
    MM(af0, 0, 2)
    __builtin_amdgcn_s_barrier();
  }

  // ---- LDS-transposed epilogue (dead 128KiB dbuf == one 256x256 bf16 tile).
  unsigned short* E = &S[0][0][0][0];   // [256][256] ushort view
  const int rg = kg * 4;
#pragma unroll
  for (int mi = 0; mi < 8; ++mi) {
#pragma unroll
    for (int nj = 0; nj < 4; ++nj) {
      const int col = wc * 64 + nj * 16 + m0;
      const float bv = bias ? bias[bn + col] : 0.0f;
      const int rowb = wr * 128 + mi * 16 + rg;
#pragma unroll
      for (int r = 0; r < 4; ++r) {
        const int row = rowb + r;
        E[row * 256 + (col ^ (((row >> 2) & 3) << 4))] = f2bf(acc[mi][nj][r] + bv);
      }
    }
  }
  __syncthreads();
#pragma unroll
  for (int jj = 0; jj < 16; ++jj) {
    const int row = jj * 16 + (tid >> 5);
    const int c0 = (tid & 31) * 8;
    const int cs = c0 ^ (((row >> 2) & 3) << 4);
    const u16x8 v = *(const u16x8*)&E[row * 256 + cs];
    *(u16x8*)&Cp[(size_t)(bm + row) * NCOLS + bn + c0] = v;
  }
}

// ---- global mask compaction scan ----
__global__ void scan_mask(const int* __restrict__ idd, int* __restrict__ sel,
                          int* __restrict__ mcount) {
  __shared__ int ps[1024];
  const int t = threadIdx.x;
  int loc[16];
  int cnt = 0;
#pragma unroll
  for (int i = 0; i < 16; ++i) {
    const int v = (idd[t * 16 + i] != 0) ? 1 : 0;
    loc[i] = v; cnt += v;
  }
  ps[t] = cnt;
  __syncthreads();
  for (int off = 1; off < 1024; off <<= 1) {
    const int add = (t >= off) ? ps[t - off] : 0;
    __syncthreads();
    ps[t] += add;
    __syncthreads();
  }
  int rank = (t == 0) ? 0 : ps[t - 1];
#pragma unroll
  for (int i = 0; i < 16; ++i)
    if (loc[i]) sel[rank++] = t * 16 + i;
  if (t == 1023) *mcount = ps[1023];
}

// ---- per-batch CSR + expanded D-list {l, idr[l], idl[l]} ----
__global__ void build_csr(const int* __restrict__ idd, const int* __restrict__ idr,
                          const int* __restrict__ idl,
                          int* __restrict__ ofsD, int* __restrict__ ofsR, int* __restrict__ ofsL,
                          int* __restrict__ lstD, int* __restrict__ lstR, int* __restrict__ lstL,
                          int4* __restrict__ lstDX) {
  __shared__ int sidx[512];
  __shared__ int scan[512];
  const int b = blockIdx.x, t = threadIdx.x;
  const int gb = b << 9;
  const int* const srcs[3] = { idd, idr, idl };
  int* const ofss[3] = { ofsD, ofsR, ofsL };
  int* const lsts[3] = { lstD, lstR, lstL };
  for (int a = 0; a < 3; ++a) {
    sidx[t] = srcs[a][gb + t];
    scan[t] = 0;
    __syncthreads();
    atomicAdd(&scan[sidx[t]], 1);
    __syncthreads();
    int v = scan[t];
    for (int off = 1; off < 512; off <<= 1) {
      const int add = (t >= off) ? scan[t - off] : 0;
      __syncthreads();
      scan[t] += add;
      __syncthreads();
    }
    const int start = scan[t] - v;
    ofss[a][b * 513 + t] = start;
    if (t == 511) ofss[a][b * 513 + 512] = scan[511];
    int pos = start;
    for (int l = 0; l < 512; ++l)
      if (sidx[l] == t) lsts[a][gb + (pos++)] = l;
    __syncthreads();
  }
  // expand D: lstDX[gb+q] = {l, idr[gb+l], idl[gb+l], 0}
  const int s0 = ofsD[b * 513 + t], s1 = ofsD[b * 513 + t + 1];
  for (int q = s0; q < s1; ++q) {
    const int l = lstD[gb + q];
    int4 e;
    e.x = l; e.y = idr[gb + l]; e.z = idl[gb + l]; e.w = 0;
    lstDX[gb + q] = e;
  }
}

// ---- fused epilogue: 2 rows/block, 8 cols/thread, expanded D-list ----
template<int REPS>
__global__ __launch_bounds__(256)
void fused_final(const unsigned short* __restrict__ gxb, const unsigned short* __restrict__ ghb,
                 const float* __restrict__ h0, const float* __restrict__ c0,
                 const int* __restrict__ idd,
                 const int* __restrict__ ofsR, const int* __restrict__ lstR,
                 const int* __restrict__ ofsL, const int* __restrict__ lstL,
                 const int* __restrict__ ofsD, const int4* __restrict__ lstDX,
                 const int* __restrict__ sel, const int* __restrict__ mcount,
                 float* __restrict__ hout, float* __restrict__ cout, int r0) {
  for (int rep = 0; rep < REPS; ++rep) {
  const int sub = threadIdx.x >> 7;          // 0/1: which row of the pair
  const int ct  = threadIdx.x & 127;
  const int r = blockIdx.x * 2 + sub;        // chunk-local row
  const int g = r0 + r;                      // global flat row
  const int j = g & 511;
  const int bb = g >> 9;
  const int lbase = (r >> 9) << 9;
  const int ob = bb * 513;
  const int lb = bb << 9;
  const int c = ct << 3;                     // 8 columns per thread

  float a[8] = {};
  for (int q = ofsR[ob + j], e = ofsR[ob + j + 1]; q < e; ++q) {
    const int l = lstR[lb + q];
    const u16x8 v = *(const u16x8*)&ghb[(size_t)(lbase + l) * NCOLS + c];
#pragma unroll
    for (int k = 0; k < 8; ++k) a[k] += bf2f(v[k]);
  }
  for (int q = ofsL[ob + j], e = ofsL[ob + j + 1]; q < e; ++q) {
    const int l = lstL[lb + q];
    const u16x8 v = *(const u16x8*)&ghb[(size_t)(lbase + l) * NCOLS + 1024 + c];
#pragma unroll
    for (int k = 0; k < 8; ++k) a[k] += bf2f(v[k]);
  }

  const u16x8 fx8 = *(const u16x8*)&gxb[(size_t)r * NCOLS + 3072 + c];
  float fx[8];
#pragma unroll
  for (int k = 0; k < 8; ++k) fx[k] = bf2f(fx8[k]);
  float fc[8] = {};
  for (int q = ofsD[ob + j], e = ofsD[ob + j + 1]; q < e; ++q) {
    const int4 dx = lstDX[lb + q];
    const int l = dx.x, jr = dx.y, jl = dx.z;
    const u16x8 rv = *(const u16x8*)&ghb[(size_t)(lbase + jr) * NCOLS + 2048 + c];
    const u16x8 lv = *(const u16x8*)&ghb[(size_t)(lbase + jl) * NCOLS + 3072 + c];
    const float4 c0a = *(const float4*)&c0[(size_t)(lb + l) * HID + c];
    const float4 c0b = *(const float4*)&c0[(size_t)(lb + l) * HID + c + 4];
    const float cc[8] = { c0a.x, c0a.y, c0a.z, c0a.w, c0b.x, c0b.y, c0b.z, c0b.w };
#pragma unroll
    for (int k = 0; k < 8; ++k)
      fc[k] += sigmoidf_(fx[k] + bf2f(rv[k]) + bf2f(lv[k])) * cc[k];
  }

  const u16x8 vi = *(const u16x8*)&gxb[(size_t)r * NCOLS + c];
  const u16x8 vo = *(const u16x8*)&gxb[(size_t)r * NCOLS + 1024 + c];
  const u16x8 vu = *(const u16x8*)&gxb[(size_t)r * NCOLS + 2048 + c];
  float hn[8], cn[8];
#pragma unroll
  for (int k = 0; k < 8; ++k) {
    const float ig = sigmoidf_(bf2f(vi[k]) + a[k]);
    const float og = sigmoidf_(bf2f(vo[k]));
    cn[k] = ig * tanhf(bf2f(vu[k])) + fc[k];
    hn[k] = og * tanhf(cn[k]);
  }

  if (idd[g] == 0) {                         // unselected rows keep h0/c0
#pragma unroll
    for (int h = 0; h < 2; ++h) {
      *(float4*)&hout[(size_t)g * HID + c + h * 4] =
          *(const float4*)&h0[(size_t)g * HID + c + h * 4];
      *(float4*)&cout[(size_t)g * HID + c + h * 4] =
          *(const float4*)&c0[(size_t)g * HID + c + h * 4];
    }
  }
  const int m = *mcount;
  if (g < m) {                               // h_new/c_new row g -> out row sel[g]
    const int o = sel[g];
    *(float4*)&hout[(size_t)o * HID + c]     = make_float4(hn[0], hn[1], hn[2], hn[3]);
    *(float4*)&hout[(size_t)o * HID + c + 4] = make_float4(hn[4], hn[5], hn[6], hn[7]);
    *(float4*)&cout[(size_t)o * HID + c]     = make_float4(cn[0], cn[1], cn[2], cn[3]);
    *(float4*)&cout[(size_t)o * HID + c + 4] = make_float4(cn[4], cn[5], cn[6], cn[7]);
  }
  asm volatile("" ::: "memory");             // prevent cross-rep collapse
  }
}

extern "C" void kernel_launch(void* const* d_in, const int* in_sizes, int n_in,
                              void* d_out, int out_size, void* d_ws, size_t ws_size,
                              hipStream_t stream) {
  const float* x      = (const float*)d_in[0];
  const float* h0     = (const float*)d_in[1];
  const float* c0     = (const float*)d_in[2];
  const float* W_ioux = (const float*)d_in[3];
  const float* W_iouh = (const float*)d_in[4];
  const float* b_iouh = (const float*)d_in[5];
  const float* W_fx   = (const float*)d_in[6];
  const float* W_fh   = (const float*)d_in[7];
  const float* b_fh   = (const float*)d_in[8];
  const int* idd      = (const int*)d_in[9];
  const int* idr      = (const int*)d_in[10];
  const int* idl      = (const int*)d_in[11];
  float* hout = (float*)d_out;
  float* cout = hout + (size_t)ROWS * HID;

  // fixed region (~17.6 MB)
  char* ws = (char*)d_ws;
  unsigned short* Wxt  = (unsigned short*)(ws);
  unsigned short* Wht  = (unsigned short*)(ws + 8388608u);
  float*          bh   = (float*)(ws + 16777216u);
  int*            sel  = (int*)(ws + 16793600u);
  int*            mcnt = (int*)(ws + 16859136u);
  int*            ofsD = (int*)(ws + 16859392u);
  int*            ofsR = (int*)(ws + 16925184u);
  int*            ofsL = (int*)(ws + 16990976u);
  int*            lstD = (int*)(ws + 17056768u);
  int*            lstR = (int*)(ws + 17122304u);
  int*            lstL = (int*)(ws + 17187840u);
  int4*           lstDX= (int4*)(ws + 17253376u);            // 256 KiB
  const size_t    base = 17515520u;

  // chunk size: largest power-of-two divisor of 32 fitting ws (10 MiB per batch)
  int C = 32;
  while (C > 1 && base + 10485760ull * (size_t)C > ws_size) C >>= 1;
  const int R = 512 * C;

  char* p = ws + base;
  unsigned short* xb  = (unsigned short*)p;  p += 1048576ull * C;
  unsigned short* hb  = (unsigned short*)p;  p += 1048576ull * C;
  unsigned short* gxb = (unsigned short*)p;  p += 4194304ull * C;
  unsigned short* ghb = (unsigned short*)p;

  pack_wx<<<dim3(128, 32), dim3(32, 32), 0, stream>>>(W_ioux, W_fx, Wxt);
  pack_wh<<<dim3(128, 32), dim3(32, 32), 0, stream>>>(W_iouh, W_fh, Wht);
  pack_bias<<<4, 1024, 0, stream>>>(b_iouh, b_fh, bh);
  scan_mask<<<1, 1024, 0, stream>>>(idd, sel, mcnt);
  build_csr<<<32, 512, 0, stream>>>(idd, idr, idl, ofsD, ofsR, ofsL,
                                    lstD, lstR, lstL, lstDX);

  for (int b0 = 0; b0 < 32; b0 += C) {
    const size_t r0 = (size_t)b0 * 512;
    convert_bf16<8><<<R, 256, 0, stream>>>(x + r0 * HID, h0 + r0 * HID, xb, hb);
    gemm8<<<dim3(NCOLS / BN, R / BM, 2), 512, 0, stream>>>(xb, hb, Wxt, Wht, gxb, ghb, bh);
    fused_final<4><<<R / 2, 256, 0, stream>>>(gxb, ghb, h0, c0, idd,
                                              ofsR, lstR, ofsL, lstL, ofsD, lstDX,
                                              sel, mcnt, hout, cout, (int)r0);
  }
}

// Round 16
// 510.274 us; speedup vs baseline: 1.3579x; 1.3579x over previous
//
#include <hip/hip_runtime.h>

// NaryTreeLSTMCell: B=32, L=512, E=H=1024.  Outputs h_out, c_out (f32, 2x16384x1024).
//
//   gx = x @ [W_ioux | W_fx]; gh = h0 @ [Wiouh0[:,:H]|Wiouh1[:,:H]|Wfh0+Wfh1|Wfh2+Wfh3]+b
//   add/fc via per-batch CSR gathers; gates -> c_new,h_new; compaction via sel[].
//
// r15 measurement: tail is BW-bound traffic (fused ~110us/460MB, convert ~40us/
// 192MB), not a slow kernel. This round: (1) revert fused_final/build_csr to the
// r7 forms (best total 527); (2) merge all 5 prep kernels into ONE grid-
// partitioned prep_all dispatch (8 -> 4 graph nodes). GEMM = r7 plateau kernel
// (303us over 10 structural variants; declared practical plateau).

#define ROWS 16384
#define HID  1024
#define KDIM 1024
#define NCOLS 4096
#define BM 256
#define BN 256

typedef __attribute__((ext_vector_type(4))) int            i32x4;
typedef __attribute__((ext_vector_type(4))) float          f32x4;
typedef __attribute__((ext_vector_type(4))) unsigned short u16x4;
typedef __attribute__((ext_vector_type(8))) unsigned short u16x8;

__device__ __forceinline__ unsigned short f2bf(float f) {
  unsigned u = __float_as_uint(f);
  unsigned r = 0x7FFFu + ((u >> 16) & 1u);
  return (unsigned short)((u + r) >> 16);
}
__device__ __forceinline__ float bf2f(unsigned short v) {
  return __uint_as_float(((unsigned)v) << 16);
}
__device__ __forceinline__ float sigmoidf_(float x) {
  return 1.0f / (1.0f + __expf(-x));
}
__device__ __forceinline__ void gload16(const void* g, void* l) {
  __builtin_amdgcn_global_load_lds(
      (const __attribute__((address_space(1))) void*)g,
      (__attribute__((address_space(3))) void*)l, 16, 0, 0);
}
__device__ __forceinline__ void mfma_bf16(f32x4& acc, i32x4 a, i32x4 b) {
  asm volatile("v_mfma_f32_16x16x32_bf16 %0, %1, %2, %0"
               : "+v"(acc) : "v"(a), "v"(b));
}

// ---- ONE prep dispatch: weight packs + bias + mask scan + per-batch CSR ----
// blocks [0,4096): pack Wxt tile; [4096,8192): pack Wht tile; [8192,8196): bias;
// 8196: scan_mask; [8197,8229): build_csr (batch = blk-8197, t<512 active).
__global__ __launch_bounds__(1024)
void prep_all(const float* __restrict__ Wioux, const float* __restrict__ Wfx,
              const float* __restrict__ Wiouh, const float* __restrict__ Wfh,
              const float* __restrict__ b_iouh, const float* __restrict__ b_fh,
              const int* __restrict__ idd, const int* __restrict__ idr,
              const int* __restrict__ idl,
              unsigned short* __restrict__ Wxt, unsigned short* __restrict__ Wht,
              float* __restrict__ bh, int* __restrict__ sel, int* __restrict__ mcnt,
              int* __restrict__ ofsD, int* __restrict__ ofsR, int* __restrict__ ofsL,
              int* __restrict__ lstD, int* __restrict__ lstR, int* __restrict__ lstL) {
  __shared__ float tt[32][33];
  __shared__ int ps[1024];
  __shared__ int sidx[512];
  __shared__ int scn[512];
  const int blk = blockIdx.x, t = threadIdx.x;

  if (blk < 4096) {              // ---- pack Wxt ----
    const int n0 = (blk & 127) * 32, k0 = (blk >> 7) * 32;
    const int tx = t & 31, ty = t >> 5;
    const int n = n0 + tx, k = k0 + ty;
    tt[ty][tx] = (n < 3072) ? Wioux[(size_t)k * 3072 + n]
                            : Wfx[(size_t)k * 1024 + (n - 3072)];
    __syncthreads();
    Wxt[(size_t)(n0 + ty) * KDIM + (k0 + tx)] = f2bf(tt[tx][ty]);
  } else if (blk < 8192) {       // ---- pack Wht ----
    const int bb = blk - 4096;
    const int n0 = (bb & 127) * 32, k0 = (bb >> 7) * 32;
    const int tx = t & 31, ty = t >> 5;
    const int n = n0 + tx, k = k0 + ty;
    float v;
    if (n < 1024)      v = Wiouh[(size_t)k * 3072 + n];
    else if (n < 2048) v = Wiouh[3145728u + (size_t)k * 3072 + (n - 1024)];
    else if (n < 3072) { const int c = n - 2048;
      v = Wfh[(size_t)k * 1024 + c] + Wfh[1048576u + (size_t)k * 1024 + c]; }
    else { const int c = n - 3072;
      v = Wfh[2097152u + (size_t)k * 1024 + c] + Wfh[3145728u + (size_t)k * 1024 + c]; }
    tt[ty][tx] = v;
    __syncthreads();
    Wht[(size_t)(n0 + ty) * KDIM + (k0 + tx)] = f2bf(tt[tx][ty]);
  } else if (blk < 8196) {       // ---- bias ----
    const int n = (blk - 8192) * 1024 + t;
    float v;
    if (n < 1024)      v = b_iouh[n];
    else if (n < 2048) v = b_iouh[3072 + (n - 1024)];
    else if (n < 3072) { const int c = n - 2048; v = b_fh[c] + b_fh[1024 + c]; }
    else { const int c = n - 3072; v = b_fh[2048 + c] + b_fh[3072 + c]; }
    bh[n] = v;
  } else if (blk == 8196) {      // ---- global mask compaction scan ----
    int loc[16];
    int cnt = 0;
#pragma unroll
    for (int i = 0; i < 16; ++i) {
      const int v = (idd[t * 16 + i] != 0) ? 1 : 0;
      loc[i] = v; cnt += v;
    }
    ps[t] = cnt;
    __syncthreads();
    for (int off = 1; off < 1024; off <<= 1) {
      const int add = (t >= off) ? ps[t - off] : 0;
      __syncthreads();
      ps[t] += add;
      __syncthreads();
    }
    int rank = (t == 0) ? 0 : ps[t - 1];
#pragma unroll
    for (int i = 0; i < 16; ++i)
      if (loc[i]) sel[rank++] = t * 16 + i;
    if (t == 1023) *mcnt = ps[1023];
  } else {                       // ---- per-batch CSR (t<512 active) ----
    const int b = blk - 8197;
    const int gb = b << 9;
    const bool act = (t < 512);
    const int* const srcs[3] = { idd, idr, idl };
    int* const ofss[3] = { ofsD, ofsR, ofsL };
    int* const lsts[3] = { lstD, lstR, lstL };
    for (int a = 0; a < 3; ++a) {
      if (act) { sidx[t] = srcs[a][gb + t]; scn[t] = 0; }
      __syncthreads();
      if (act) atomicAdd(&scn[sidx[t]], 1);
      __syncthreads();
      const int v = act ? scn[t] : 0;
      for (int off = 1; off < 512; off <<= 1) {
        const int add = (act && t >= off) ? scn[t - off] : 0;
        __syncthreads();
        if (act) scn[t] += add;
        __syncthreads();
      }
      if (act) {
        const int start = scn[t] - v;
        ofss[a][b * 513 + t] = start;
        if (t == 511) ofss[a][b * 513 + 512] = scn[511];
        int pos = start;
        for (int l = 0; l < 512; ++l)
          if (sidx[l] == t) lsts[a][gb + (pos++)] = l;
      }
      __syncthreads();
    }
  }
}

__global__ void convert_bf16(const float* __restrict__ x, const float* __restrict__ h0,
                             unsigned short* __restrict__ xb, unsigned short* __restrict__ hb) {
  const size_t i = ((size_t)blockIdx.x * 256 + threadIdx.x) * 4;
  const float4 a = *(const float4*)&x[i];
  const float4 b = *(const float4*)&h0[i];
  u16x4 av = { f2bf(a.x), f2bf(a.y), f2bf(a.z), f2bf(a.w) };
  u16x4 bv = { f2bf(b.x), f2bf(b.y), f2bf(b.z), f2bf(b.w) };
  *(u16x4*)&xb[i] = av;
  *(u16x4*)&hb[i] = bv;
}

// stage8: one gload16 per wave = 8 rows x 64B. Global seg pre-swizzled ^(row&7);
// LDS stays linear (global_load_lds constraint). rowbase multiple of 8.
__device__ __forceinline__ void stage8(const unsigned short* __restrict__ gp,
                                       unsigned short* __restrict__ lp,
                                       int rowbase, int gbase, int k0, int lane) {
  const int lrow = rowbase + (lane >> 3);
  const int sseg = (lane & 7) ^ ((lane >> 3) & 7);
  gload16(gp + (size_t)(gbase + lrow) * KDIM + k0 + sseg * 8,
          lp + ((size_t)rowbase << 6));
}

#define RD_A(dst, qm)                                                          \
  _Pragma("unroll")                                                            \
  for (int i = 0; i < 4; ++i) {                                                \
    const int row = wr * 128 + (qm) * 64 + i * 16 + m0;                        \
    _Pragma("unroll")                                                          \
    for (int s = 0; s < 2; ++s)                                                \
      dst[i][s] = *(const i32x4*)(Ab + row * 64 + (((kg + s * 4) ^ sw8) << 3)); \
  }

#define RD_B(dst, qn)                                                          \
  _Pragma("unroll")                                                            \
  for (int j = 0; j < 2; ++j) {                                                \
    const int col = wc * 64 + (qn) * 32 + j * 16 + m0;                         \
    _Pragma("unroll")                                                          \
    for (int s = 0; s < 2; ++s)                                                \
      dst[j][s] = *(const i32x4*)(Bb + col * 64 + (((kg + s * 4) ^ sw8) << 3)); \
  }

#define MM(afx, qmb, qnb)                                                      \
  __builtin_amdgcn_s_setprio(1);                                               \
  _Pragma("unroll")                                                            \
  for (int i = 0; i < 4; ++i)                                                  \
    _Pragma("unroll")                                                          \
    for (int j = 0; j < 2; ++j) {                                              \
      mfma_bf16(acc[(qmb) + i][(qnb) + j], afx[i][0], bfr[j][0]);              \
      mfma_bf16(acc[(qmb) + i][(qnb) + j], afx[i][1], bfr[j][1]);              \
    }                                                                          \
  __builtin_amdgcn_s_setprio(0);

__global__ __launch_bounds__(512, 2)
void gemm8(const unsigned short* __restrict__ xb, const unsigned short* __restrict__ hb,
           const unsigned short* __restrict__ Wxt, const unsigned short* __restrict__ Wht,
           unsigned short* __restrict__ gxb, unsigned short* __restrict__ ghb,
           const float* __restrict__ bhv) {
  __shared__ __align__(16) unsigned short S[2][2][256][64];  // [buf][A|B][row][64]

  const unsigned short* A;
  const unsigned short* Bt;
  unsigned short* Cp;
  const float* bias;
  if (blockIdx.z == 0) { A = xb; Bt = Wxt; Cp = gxb; bias = nullptr; }
  else                 { A = hb; Bt = Wht; Cp = ghb; bias = bhv; }

  // T1 XCD-aware swizzle (bijective; ny multiple of 8), y-major within chunk.
  int bx = blockIdx.x, by = blockIdx.y;
  const int ny = gridDim.y;
  if ((ny & 7) == 0) {
    const int n = blockIdx.x + 16 * blockIdx.y;
    const int xcd = n & 7, idx = n >> 3;
    const int ych = ny >> 3;
    bx = idx / ych;
    by = xcd * ych + (idx % ych);
  }
  const int bm = by * BM, bn = bx * BN;

  const int tid = threadIdx.x, w = tid >> 6, lane = tid & 63;
  const int wr = w >> 2, wc = w & 3;
  const int m0 = lane & 15, kg = lane >> 4, sw8 = m0 & 7;
  const int bq0 = ((w >> 1) << 6) + ((w & 1) << 4);

  f32x4 acc[8][4] = {};

  // prologue: stage all of tile 0 into buf 0, drain once
  stage8(A,  &S[0][0][0][0], w * 8,        bm, 0, lane);
  stage8(A,  &S[0][0][0][0], 128 + w * 8,  bm, 0, lane);
  stage8(A,  &S[0][0][0][0], 64 + w * 8,   bm, 0, lane);
  stage8(A,  &S[0][0][0][0], 192 + w * 8,  bm, 0, lane);
  stage8(Bt, &S[0][1][0][0], bq0,          bn, 0, lane);
  stage8(Bt, &S[0][1][0][0], bq0 + 8,      bn, 0, lane);
  stage8(Bt, &S[0][1][0][0], bq0 + 32,     bn, 0, lane);
  stage8(Bt, &S[0][1][0][0], bq0 + 40,     bn, 0, lane);
  asm volatile("s_waitcnt vmcnt(0)" ::: "memory");
  __builtin_amdgcn_s_barrier();

  for (int t = 0; t < 16; ++t) {
    const int cur = t & 1, nxt = cur ^ 1;
    const unsigned short* Ab = &S[cur][0][0][0];
    const unsigned short* Bb = &S[cur][1][0][0];
    unsigned short* An = &S[nxt][0][0][0];
    unsigned short* Bn = &S[nxt][1][0][0];
    const int k1 = (t + 1) << 6;
    const bool st = (t < 15);
    i32x4 af0[4][2], af1[4][2], bfr[2][2];

    // ---- P0 (qm0,qn0): rd af0+bfr0; stage A0(t+1); retire A1(t) ----
    RD_A(af0, 0)
    RD_B(bfr, 0)
    if (st) { stage8(A, An, w * 8, bm, k1, lane);
              stage8(A, An, 128 + w * 8, bm, k1, lane);
              asm volatile("s_waitcnt vmcnt(4)" ::: "memory"); }
    else    { asm volatile("s_waitcnt vmcnt(2)" ::: "memory"); }
    __builtin_amdgcn_s_barrier();
    MM(af0, 0, 0)
    __builtin_amdgcn_s_barrier();

    // ---- P1 (qm1,qn0): rd af1; stage B0(t+1); retire B1(t) ----
    RD_A(af1, 1)
    if (st) { stage8(Bt, Bn, bq0, bn, k1, lane);
              stage8(Bt, Bn, bq0 + 8, bn, k1, lane);
              asm volatile("s_waitcnt vmcnt(4)" ::: "memory"); }
    else    { asm volatile("s_waitcnt vmcnt(0)" ::: "memory"); }
    __builtin_amdgcn_s_barrier();
    MM(af1, 4, 0)
    __builtin_amdgcn_s_barrier();

    // ---- P2 (qm1,qn1): rd bfr1; stage A1(t+1); no wait ----
    RD_B(bfr, 1)
    if (st) { stage8(A, An, 64 + w * 8, bm, k1, lane);
              stage8(A, An, 192 + w * 8, bm, k1, lane); }
    __builtin_amdgcn_s_barrier();
    MM(af1, 4, 2)
    __builtin_amdgcn_s_barrier();

    // ---- P3 (qm0,qn1): no reads; stage B1(t+1); retire A0/B0(t+1) ----
    if (st) { stage8(Bt, Bn, bq0 + 32, bn, k1, lane);
              stage8(Bt, Bn, bq0 + 40, bn, k1, lane);
              asm volatile("s_waitcnt vmcnt(4)" ::: "memory"); }
    __builtin_amdgcn_s_barrier();
    MM(af0, 0, 2)
    __builtin_amdgcn_s_barrier();
  }

  // ---- LDS-transposed epilogue (dead 128KiB dbuf == one 256x256 bf16 tile).
  unsigned short* E = &S[0][0][0][0];   // [256][256] ushort view
  const int rg = kg * 4;
#pragma unroll
  for (int mi = 0; mi < 8; ++mi) {
#pragma unroll
    for (int nj = 0; nj < 4; ++nj) {
      const int col = wc * 64 + nj * 16 + m0;
      const float bv = bias ? bias[bn + col] : 0.0f;
      const int rowb = wr * 128 + mi * 16 + rg;
#pragma unroll
      for (int r = 0; r < 4; ++r) {
        const int row = rowb + r;
        E[row * 256 + (col ^ (((row >> 2) & 3) << 4))] = f2bf(acc[mi][nj][r] + bv);
      }
    }
  }
  __syncthreads();
#pragma unroll
  for (int jj = 0; jj < 16; ++jj) {
    const int row = jj * 16 + (tid >> 5);
    const int c0 = (tid & 31) * 8;
    const int cs = c0 ^ (((row >> 2) & 3) << 4);
    const u16x8 v = *(const u16x8*)&E[row * 256 + cs];
    *(u16x8*)&Cp[(size_t)(bm + row) * NCOLS + bn + c0] = v;
  }
}

// ---- fused epilogue (r7 form): gather-add + f-gate + activations + compaction ----
__global__ __launch_bounds__(256)
void fused_final(const unsigned short* __restrict__ gxb, const unsigned short* __restrict__ ghb,
                 const float* __restrict__ h0, const float* __restrict__ c0,
                 const int* __restrict__ idd, const int* __restrict__ idr,
                 const int* __restrict__ idl,
                 const int* __restrict__ ofsR, const int* __restrict__ lstR,
                 const int* __restrict__ ofsL, const int* __restrict__ lstL,
                 const int* __restrict__ ofsD, const int* __restrict__ lstD,
                 const int* __restrict__ sel, const int* __restrict__ mcount,
                 float* __restrict__ hout, float* __restrict__ cout, int r0) {
  const int r = blockIdx.x;
  const int g = r0 + r;
  const int j = g & 511;
  const int bb = g >> 9;
  const int lbase = (r >> 9) << 9;
  const int ob = bb * 513;
  const int lb = bb << 9;
  const int c = threadIdx.x << 2;

  float a0 = 0.f, a1 = 0.f, a2 = 0.f, a3 = 0.f;
  for (int q = ofsR[ob + j], e = ofsR[ob + j + 1]; q < e; ++q) {
    const int l = lstR[lb + q];
    const u16x4 v = *(const u16x4*)&ghb[(size_t)(lbase + l) * NCOLS + c];
    a0 += bf2f(v[0]); a1 += bf2f(v[1]); a2 += bf2f(v[2]); a3 += bf2f(v[3]);
  }
  for (int q = ofsL[ob + j], e = ofsL[ob + j + 1]; q < e; ++q) {
    const int l = lstL[lb + q];
    const u16x4 v = *(const u16x4*)&ghb[(size_t)(lbase + l) * NCOLS + 1024 + c];
    a0 += bf2f(v[0]); a1 += bf2f(v[1]); a2 += bf2f(v[2]); a3 += bf2f(v[3]);
  }

  const u16x4 fx4 = *(const u16x4*)&gxb[(size_t)r * NCOLS + 3072 + c];
  const float fx0 = bf2f(fx4[0]), fx1 = bf2f(fx4[1]), fx2 = bf2f(fx4[2]), fx3 = bf2f(fx4[3]);
  float fc0 = 0.f, fc1 = 0.f, fc2 = 0.f, fc3 = 0.f;
  for (int q = ofsD[ob + j], e = ofsD[ob + j + 1]; q < e; ++q) {
    const int l = lstD[lb + q];
    const int jr = idr[lb + l], jl = idl[lb + l];
    const u16x4 rv = *(const u16x4*)&ghb[(size_t)(lbase + jr) * NCOLS + 2048 + c];
    const u16x4 lv = *(const u16x4*)&ghb[(size_t)(lbase + jl) * NCOLS + 3072 + c];
    const float4 cc = *(const float4*)&c0[(size_t)(lb + l) * HID + c];
    fc0 += sigmoidf_(fx0 + bf2f(rv[0]) + bf2f(lv[0])) * cc.x;
    fc1 += sigmoidf_(fx1 + bf2f(rv[1]) + bf2f(lv[1])) * cc.y;
    fc2 += sigmoidf_(fx2 + bf2f(rv[2]) + bf2f(lv[2])) * cc.z;
    fc3 += sigmoidf_(fx3 + bf2f(rv[3]) + bf2f(lv[3])) * cc.w;
  }

  const u16x4 vi = *(const u16x4*)&gxb[(size_t)r * NCOLS + c];
  const u16x4 vo = *(const u16x4*)&gxb[(size_t)r * NCOLS + 1024 + c];
  const u16x4 vu = *(const u16x4*)&gxb[(size_t)r * NCOLS + 2048 + c];
  float4 hn, cn;
  {
    const float ig = sigmoidf_(bf2f(vi[0]) + a0), og = sigmoidf_(bf2f(vo[0]));
    cn.x = ig * tanhf(bf2f(vu[0])) + fc0; hn.x = og * tanhf(cn.x);
  }
  {
    const float ig = sigmoidf_(bf2f(vi[1]) + a1), og = sigmoidf_(bf2f(vo[1]));
    cn.y = ig * tanhf(bf2f(vu[1])) + fc1; hn.y = og * tanhf(cn.y);
  }
  {
    const float ig = sigmoidf_(bf2f(vi[2]) + a2), og = sigmoidf_(bf2f(vo[2]));
    cn.z = ig * tanhf(bf2f(vu[2])) + fc2; hn.z = og * tanhf(cn.z);
  }
  {
    const float ig = sigmoidf_(bf2f(vi[3]) + a3), og = sigmoidf_(bf2f(vo[3]));
    cn.w = ig * tanhf(bf2f(vu[3])) + fc3; hn.w = og * tanhf(cn.w);
  }

  if (idd[g] == 0) {
    *(float4*)&hout[(size_t)g * HID + c] = *(const float4*)&h0[(size_t)g * HID + c];
    *(float4*)&cout[(size_t)g * HID + c] = *(const float4*)&c0[(size_t)g * HID + c];
  }
  const int m = *mcount;
  if (g < m) {
    const int o = sel[g];
    *(float4*)&hout[(size_t)o * HID + c] = hn;
    *(float4*)&cout[(size_t)o * HID + c] = cn;
  }
}

extern "C" void kernel_launch(void* const* d_in, const int* in_sizes, int n_in,
                              void* d_out, int out_size, void* d_ws, size_t ws_size,
                              hipStream_t stream) {
  const float* x      = (const float*)d_in[0];
  const float* h0     = (const float*)d_in[1];
  const float* c0     = (const float*)d_in[2];
  const float* W_ioux = (const float*)d_in[3];
  const float* W_iouh = (const float*)d_in[4];
  const float* b_iouh = (const float*)d_in[5];
  const float* W_fx   = (const float*)d_in[6];
  const float* W_fh   = (const float*)d_in[7];
  const float* b_fh   = (const float*)d_in[8];
  const int* idd      = (const int*)d_in[9];
  const int* idr      = (const int*)d_in[10];
  const int* idl      = (const int*)d_in[11];
  float* hout = (float*)d_out;
  float* cout = hout + (size_t)ROWS * HID;

  // fixed region (~17.3 MB)
  char* ws = (char*)d_ws;
  unsigned short* Wxt  = (unsigned short*)(ws);
  unsigned short* Wht  = (unsigned short*)(ws + 8388608u);
  float*          bh   = (float*)(ws + 16777216u);
  int*            sel  = (int*)(ws + 16793600u);
  int*            mcnt = (int*)(ws + 16859136u);
  int*            ofsD = (int*)(ws + 16859392u);
  int*            ofsR = (int*)(ws + 16925184u);
  int*            ofsL = (int*)(ws + 16990976u);
  int*            lstD = (int*)(ws + 17056768u);
  int*            lstR = (int*)(ws + 17122304u);
  int*            lstL = (int*)(ws + 17187840u);
  const size_t    base = 17253376u;

  // chunk size: largest power-of-two divisor of 32 fitting ws (10 MiB per batch)
  int C = 32;
  while (C > 1 && base + 10485760ull * (size_t)C > ws_size) C >>= 1;
  const int R = 512 * C;

  char* p = ws + base;
  unsigned short* xb  = (unsigned short*)p;  p += 1048576ull * C;
  unsigned short* hb  = (unsigned short*)p;  p += 1048576ull * C;
  unsigned short* gxb = (unsigned short*)p;  p += 4194304ull * C;
  unsigned short* ghb = (unsigned short*)p;

  prep_all<<<8229, 1024, 0, stream>>>(W_ioux, W_fx, W_iouh, W_fh, b_iouh, b_fh,
                                      idd, idr, idl, Wxt, Wht, bh, sel, mcnt,
                                      ofsD, ofsR, ofsL, lstD, lstR, lstL);

  for (int b0 = 0; b0 < 32; b0 += C) {
    const size_t r0 = (size_t)b0 * 512;
    convert_bf16<<<R, 256, 0, stream>>>(x + r0 * HID, h0 + r0 * HID, xb, hb);
    gemm8<<<dim3(NCOLS / BN, R / BM, 2), 512, 0, stream>>>(xb, hb, Wxt, Wht, gxb, ghb, bh);
    fused_final<<<R, 256, 0, stream>>>(gxb, ghb, h0, c0, idd, idr, idl,
                                       ofsR, lstR, ofsL, lstL, ofsD, lstD,
                                       sel, mcnt, hout, cout, (int)r0);
  }
}

// Round 17
// 508.956 us; speedup vs baseline: 1.3614x; 1.0026x over previous
//
#include <hip/hip_runtime.h>

// NaryTreeLSTMCell: B=32, L=512, E=H=1024.  Outputs h_out, c_out (f32, 2x16384x1024).
//
//   gx = x @ [W_ioux | W_fx]; gh = h0 @ [Wiouh0[:,:H]|Wiouh1[:,:H]|Wfh0+Wfh1|Wfh2+Wfh3]+b
//   add/fc via per-batch CSR gathers; gates -> c_new,h_new; compaction via sel[].
//
// r15 measurement: tail is BW-bound traffic (fused ~110us/460MB, convert ~40us/
// 192MB), not a slow kernel. This round: (1) revert fused_final/build_csr to the
// r7 forms (best total 527); (2) merge all 5 prep kernels into ONE grid-
// partitioned prep_all dispatch (8 -> 4 graph nodes). GEMM = r7 plateau kernel
// (303us over 10 structural variants; declared practical plateau).

#define ROWS 16384
#define HID  1024
#define KDIM 1024
#define NCOLS 4096
#define BM 256
#define BN 256

typedef __attribute__((ext_vector_type(4))) int            i32x4;
typedef __attribute__((ext_vector_type(4))) float          f32x4;
typedef __attribute__((ext_vector_type(4))) unsigned short u16x4;
typedef __attribute__((ext_vector_type(8))) unsigned short u16x8;

__device__ __forceinline__ unsigned short f2bf(float f) {
  unsigned u = __float_as_uint(f);
  unsigned r = 0x7FFFu + ((u >> 16) & 1u);
  return (unsigned short)((u + r) >> 16);
}
__device__ __forceinline__ float bf2f(unsigned short v) {
  return __uint_as_float(((unsigned)v) << 16);
}
__device__ __forceinline__ float sigmoidf_(float x) {
  return 1.0f / (1.0f + __expf(-x));
}
__device__ __forceinline__ void gload16(const void* g, void* l) {
  __builtin_amdgcn_global_load_lds(
      (const __attribute__((address_space(1))) void*)g,
      (__attribute__((address_space(3))) void*)l, 16, 0, 0);
}
__device__ __forceinline__ void mfma_bf16(f32x4& acc, i32x4 a, i32x4 b) {
  asm volatile("v_mfma_f32_16x16x32_bf16 %0, %1, %2, %0"
               : "+v"(acc) : "v"(a), "v"(b));
}

// ---- ONE prep dispatch: weight packs + bias + mask scan + per-batch CSR ----
// blocks [0,4096): pack Wxt tile; [4096,8192): pack Wht tile; [8192,8196): bias;
// 8196: scan_mask; [8197,8229): build_csr (batch = blk-8197, t<512 active).
__global__ __launch_bounds__(1024)
void prep_all(const float* __restrict__ Wioux, const float* __restrict__ Wfx,
              const float* __restrict__ Wiouh, const float* __restrict__ Wfh,
              const float* __restrict__ b_iouh, const float* __restrict__ b_fh,
              const int* __restrict__ idd, const int* __restrict__ idr,
              const int* __restrict__ idl,
              unsigned short* __restrict__ Wxt, unsigned short* __restrict__ Wht,
              float* __restrict__ bh, int* __restrict__ sel, int* __restrict__ mcnt,
              int* __restrict__ ofsD, int* __restrict__ ofsR, int* __restrict__ ofsL,
              int* __restrict__ lstD, int* __restrict__ lstR, int* __restrict__ lstL) {
  __shared__ float tt[32][33];
  __shared__ int ps[1024];
  __shared__ int sidx[512];
  __shared__ int scn[512];
  const int blk = blockIdx.x, t = threadIdx.x;

  if (blk < 4096) {              // ---- pack Wxt ----
    const int n0 = (blk & 127) * 32, k0 = (blk >> 7) * 32;
    const int tx = t & 31, ty = t >> 5;
    const int n = n0 + tx, k = k0 + ty;
    tt[ty][tx] = (n < 3072) ? Wioux[(size_t)k * 3072 + n]
                            : Wfx[(size_t)k * 1024 + (n - 3072)];
    __syncthreads();
    Wxt[(size_t)(n0 + ty) * KDIM + (k0 + tx)] = f2bf(tt[tx][ty]);
  } else if (blk < 8192) {       // ---- pack Wht ----
    const int bb = blk - 4096;
    const int n0 = (bb & 127) * 32, k0 = (bb >> 7) * 32;
    const int tx = t & 31, ty = t >> 5;
    const int n = n0 + tx, k = k0 + ty;
    float v;
    if (n < 1024)      v = Wiouh[(size_t)k * 3072 + n];
    else if (n < 2048) v = Wiouh[3145728u + (size_t)k * 3072 + (n - 1024)];
    else if (n < 3072) { const int c = n - 2048;
      v = Wfh[(size_t)k * 1024 + c] + Wfh[1048576u + (size_t)k * 1024 + c]; }
    else { const int c = n - 3072;
      v = Wfh[2097152u + (size_t)k * 1024 + c] + Wfh[3145728u + (size_t)k * 1024 + c]; }
    tt[ty][tx] = v;
    __syncthreads();
    Wht[(size_t)(n0 + ty) * KDIM + (k0 + tx)] = f2bf(tt[tx][ty]);
  } else if (blk < 8196) {       // ---- bias ----
    const int n = (blk - 8192) * 1024 + t;
    float v;
    if (n < 1024)      v = b_iouh[n];
    else if (n < 2048) v = b_iouh[3072 + (n - 1024)];
    else if (n < 3072) { const int c = n - 2048; v = b_fh[c] + b_fh[1024 + c]; }
    else { const int c = n - 3072; v = b_fh[2048 + c] + b_fh[3072 + c]; }
    bh[n] = v;
  } else if (blk == 8196) {      // ---- global mask compaction scan ----
    int loc[16];
    int cnt = 0;
#pragma unroll
    for (int i = 0; i < 16; ++i) {
      const int v = (idd[t * 16 + i] != 0) ? 1 : 0;
      loc[i] = v; cnt += v;
    }
    ps[t] = cnt;
    __syncthreads();
    for (int off = 1; off < 1024; off <<= 1) {
      const int add = (t >= off) ? ps[t - off] : 0;
      __syncthreads();
      ps[t] += add;
      __syncthreads();
    }
    int rank = (t == 0) ? 0 : ps[t - 1];
#pragma unroll
    for (int i = 0; i < 16; ++i)
      if (loc[i]) sel[rank++] = t * 16 + i;
    if (t == 1023) *mcnt = ps[1023];
  } else {                       // ---- per-batch CSR (t<512 active) ----
    const int b = blk - 8197;
    const int gb = b << 9;
    const bool act = (t < 512);
    const int* const srcs[3] = { idd, idr, idl };
    int* const ofss[3] = { ofsD, ofsR, ofsL };
    int* const lsts[3] = { lstD, lstR, lstL };
    for (int a = 0; a < 3; ++a) {
      if (act) { sidx[t] = srcs[a][gb + t]; scn[t] = 0; }
      __syncthreads();
      if (act) atomicAdd(&scn[sidx[t]], 1);
      __syncthreads();
      const int v = act ? scn[t] : 0;
      for (int off = 1; off < 512; off <<= 1) {
        const int add = (act && t >= off) ? scn[t - off] : 0;
        __syncthreads();
        if (act) scn[t] += add;
        __syncthreads();
      }
      if (act) {
        const int start = scn[t] - v;
        ofss[a][b * 513 + t] = start;
        if (t == 511) ofss[a][b * 513 + 512] = scn[511];
        int pos = start;
        for (int l = 0; l < 512; ++l)
          if (sidx[l] == t) lsts[a][gb + (pos++)] = l;
      }
      __syncthreads();
    }
  }
}

__global__ void convert_bf16(const float* __restrict__ x, const float* __restrict__ h0,
                             unsigned short* __restrict__ xb, unsigned short* __restrict__ hb) {
  const size_t i = ((size_t)blockIdx.x * 256 + threadIdx.x) * 4;
  const float4 a = *(const float4*)&x[i];
  const float4 b = *(const float4*)&h0[i];
  u16x4 av = { f2bf(a.x), f2bf(a.y), f2bf(a.z), f2bf(a.w) };
  u16x4 bv = { f2bf(b.x), f2bf(b.y), f2bf(b.z), f2bf(b.w) };
  *(u16x4*)&xb[i] = av;
  *(u16x4*)&hb[i] = bv;
}

// stage8: one gload16 per wave = 8 rows x 64B. Global seg pre-swizzled ^(row&7);
// LDS stays linear (global_load_lds constraint). rowbase multiple of 8.
__device__ __forceinline__ void stage8(const unsigned short* __restrict__ gp,
                                       unsigned short* __restrict__ lp,
                                       int rowbase, int gbase, int k0, int lane) {
  const int lrow = rowbase + (lane >> 3);
  const int sseg = (lane & 7) ^ ((lane >> 3) & 7);
  gload16(gp + (size_t)(gbase + lrow) * KDIM + k0 + sseg * 8,
          lp + ((size_t)rowbase << 6));
}

#define RD_A(dst, qm)                                                          \
  _Pragma("unroll")                                                            \
  for (int i = 0; i < 4; ++i) {                                                \
    const int row = wr * 128 + (qm) * 64 + i * 16 + m0;                        \
    _Pragma("unroll")                                                          \
    for (int s = 0; s < 2; ++s)                                                \
      dst[i][s] = *(const i32x4*)(Ab + row * 64 + (((kg + s * 4) ^ sw8) << 3)); \
  }

#define RD_B(dst, qn)                                                          \
  _Pragma("unroll")                                                            \
  for (int j = 0; j < 2; ++j) {                                                \
    const int col = wc * 64 + (qn) * 32 + j * 16 + m0;                         \
    _Pragma("unroll")                                                          \
    for (int s = 0; s < 2; ++s)                                                \
      dst[j][s] = *(const i32x4*)(Bb + col * 64 + (((kg + s * 4) ^ sw8) << 3)); \
  }

#define MM(afx, qmb, qnb)                                                      \
  __builtin_amdgcn_s_setprio(1);                                               \
  _Pragma("unroll")                                                            \
  for (int i = 0; i < 4; ++i)                                                  \
    _Pragma("unroll")                                                          \
    for (int j = 0; j < 2; ++j) {                                              \
      mfma_bf16(acc[(qmb) + i][(qnb) + j], afx[i][0], bfr[j][0]);              \
      mfma_bf16(acc[(qmb) + i][(qnb) + j], afx[i][1], bfr[j][1]);              \
    }                                                                          \
  __builtin_amdgcn_s_setprio(0);

__global__ __launch_bounds__(512, 2)
void gemm8(const unsigned short* __restrict__ xb, const unsigned short* __restrict__ hb,
           const unsigned short* __restrict__ Wxt, const unsigned short* __restrict__ Wht,
           unsigned short* __restrict__ gxb, unsigned short* __restrict__ ghb,
           const float* __restrict__ bhv) {
  __shared__ __align__(16) unsigned short S[2][2][256][64];  // [buf][A|B][row][64]

  const unsigned short* A;
  const unsigned short* Bt;
  unsigned short* Cp;
  const float* bias;
  if (blockIdx.z == 0) { A = xb; Bt = Wxt; Cp = gxb; bias = nullptr; }
  else                 { A = hb; Bt = Wht; Cp = ghb; bias = bhv; }

  // T1 XCD-aware swizzle (bijective; ny multiple of 8), y-major within chunk.
  int bx = blockIdx.x, by = blockIdx.y;
  const int ny = gridDim.y;
  if ((ny & 7) == 0) {
    const int n = blockIdx.x + 16 * blockIdx.y;
    const int xcd = n & 7, idx = n >> 3;
    const int ych = ny >> 3;
    bx = idx / ych;
    by = xcd * ych + (idx % ych);
  }
  const int bm = by * BM, bn = bx * BN;

  const int tid = threadIdx.x, w = tid >> 6, lane = tid & 63;
  const int wr = w >> 2, wc = w & 3;
  const int m0 = lane & 15, kg = lane >> 4, sw8 = m0 & 7;
  const int bq0 = ((w >> 1) << 6) + ((w & 1) << 4);

  f32x4 acc[8][4] = {};

  // prologue: stage all of tile 0 into buf 0, drain once
  stage8(A,  &S[0][0][0][0], w * 8,        bm, 0, lane);
  stage8(A,  &S[0][0][0][0], 128 + w * 8,  bm, 0, lane);
  stage8(A,  &S[0][0][0][0], 64 + w * 8,   bm, 0, lane);
  stage8(A,  &S[0][0][0][0], 192 + w * 8,  bm, 0, lane);
  stage8(Bt, &S[0][1][0][0], bq0,          bn, 0, lane);
  stage8(Bt, &S[0][1][0][0], bq0 + 8,      bn, 0, lane);
  stage8(Bt, &S[0][1][0][0], bq0 + 32,     bn, 0, lane);
  stage8(Bt, &S[0][1][0][0], bq0 + 40,     bn, 0, lane);
  asm volatile("s_waitcnt vmcnt(0)" ::: "memory");
  __builtin_amdgcn_s_barrier();

  for (int t = 0; t < 16; ++t) {
    const int cur = t & 1, nxt = cur ^ 1;
    const unsigned short* Ab = &S[cur][0][0][0];
    const unsigned short* Bb = &S[cur][1][0][0];
    unsigned short* An = &S[nxt][0][0][0];
    unsigned short* Bn = &S[nxt][1][0][0];
    const int k1 = (t + 1) << 6;
    const bool st = (t < 15);
    i32x4 af0[4][2], af1[4][2], bfr[2][2];

    // ---- P0 (qm0,qn0): rd af0+bfr0; stage A0(t+1); retire A1(t) ----
    RD_A(af0, 0)
    RD_B(bfr, 0)
    if (st) { stage8(A, An, w * 8, bm, k1, lane);
              stage8(A, An, 128 + w * 8, bm, k1, lane);
              asm volatile("s_waitcnt vmcnt(4)" ::: "memory"); }
    else    { asm volatile("s_waitcnt vmcnt(2)" ::: "memory"); }
    __builtin_amdgcn_s_barrier();
    MM(af0, 0, 0)
    __builtin_amdgcn_s_barrier();

    // ---- P1 (qm1,qn0): rd af1; stage B0(t+1); retire B1(t) ----
    RD_A(af1, 1)
    if (st) { stage8(Bt, Bn, bq0, bn, k1, lane);
              stage8(Bt, Bn, bq0 + 8, bn, k1, lane);
              asm volatile("s_waitcnt vmcnt(4)" ::: "memory"); }
    else    { asm volatile("s_waitcnt vmcnt(0)" ::: "memory"); }
    __builtin_amdgcn_s_barrier();
    MM(af1, 4, 0)
    __builtin_amdgcn_s_barrier();

    // ---- P2 (qm1,qn1): rd bfr1; stage A1(t+1); no wait ----
    RD_B(bfr, 1)
    if (st) { stage8(A, An, 64 + w * 8, bm, k1, lane);
              stage8(A, An, 192 + w * 8, bm, k1, lane); }
    __builtin_amdgcn_s_barrier();
    MM(af1, 4, 2)
    __builtin_amdgcn_s_barrier();

    // ---- P3 (qm0,qn1): no reads; stage B1(t+1); retire A0/B0(t+1) ----
    if (st) { stage8(Bt, Bn, bq0 + 32, bn, k1, lane);
              stage8(Bt, Bn, bq0 + 40, bn, k1, lane);
              asm volatile("s_waitcnt vmcnt(4)" ::: "memory"); }
    __builtin_amdgcn_s_barrier();
    MM(af0, 0, 2)
    __builtin_amdgcn_s_barrier();
  }

  // ---- LDS-transposed epilogue (dead 128KiB dbuf == one 256x256 bf16 tile).
  unsigned short* E = &S[0][0][0][0];   // [256][256] ushort view
  const int rg = kg * 4;
#pragma unroll
  for (int mi = 0; mi < 8; ++mi) {
#pragma unroll
    for (int nj = 0; nj < 4; ++nj) {
      const int col = wc * 64 + nj * 16 + m0;
      const float bv = bias ? bias[bn + col] : 0.0f;
      const int rowb = wr * 128 + mi * 16 + rg;
#pragma unroll
      for (int r = 0; r < 4; ++r) {
        const int row = rowb + r;
        E[row * 256 + (col ^ (((row >> 2) & 3) << 4))] = f2bf(acc[mi][nj][r] + bv);
      }
    }
  }
  __syncthreads();
#pragma unroll
  for (int jj = 0; jj < 16; ++jj) {
    const int row = jj * 16 + (tid >> 5);
    const int c0 = (tid & 31) * 8;
    const int cs = c0 ^ (((row >> 2) & 3) << 4);
    const u16x8 v = *(const u16x8*)&E[row * 256 + cs];
    *(u16x8*)&Cp[(size_t)(bm + row) * NCOLS + bn + c0] = v;
  }
}

// ---- fused epilogue (r7 form): gather-add + f-gate + activations + compaction ----
__global__ __launch_bounds__(256)
void fused_final(const unsigned short* __restrict__ gxb, const unsigned short* __restrict__ ghb,
                 const float* __restrict__ h0, const float* __restrict__ c0,
                 const int* __restrict__ idd, const int* __restrict__ idr,
                 const int* __restrict__ idl,
                 const int* __restrict__ ofsR, const int* __restrict__ lstR,
                 const int* __restrict__ ofsL, const int* __restrict__ lstL,
                 const int* __restrict__ ofsD, const int* __restrict__ lstD,
                 const int* __restrict__ sel, const int* __restrict__ mcount,
                 float* __restrict__ hout, float* __restrict__ cout, int r0) {
  const int r = blockIdx.x;
  const int g = r0 + r;
  const int j = g & 511;
  const int bb = g >> 9;
  const int lbase = (r >> 9) << 9;
  const int ob = bb * 513;
  const int lb = bb << 9;
  const int c = threadIdx.x << 2;

  float a0 = 0.f, a1 = 0.f, a2 = 0.f, a3 = 0.f;
  for (int q = ofsR[ob + j], e = ofsR[ob + j + 1]; q < e; ++q) {
    const int l = lstR[lb + q];
    const u16x4 v = *(const u16x4*)&ghb[(size_t)(lbase + l) * NCOLS + c];
    a0 += bf2f(v[0]); a1 += bf2f(v[1]); a2 += bf2f(v[2]); a3 += bf2f(v[3]);
  }
  for (int q = ofsL[ob + j], e = ofsL[ob + j + 1]; q < e; ++q) {
    const int l = lstL[lb + q];
    const u16x4 v = *(const u16x4*)&ghb[(size_t)(lbase + l) * NCOLS + 1024 + c];
    a0 += bf2f(v[0]); a1 += bf2f(v[1]); a2 += bf2f(v[2]); a3 += bf2f(v[3]);
  }

  const u16x4 fx4 = *(const u16x4*)&gxb[(size_t)r * NCOLS + 3072 + c];
  const float fx0 = bf2f(fx4[0]), fx1 = bf2f(fx4[1]), fx2 = bf2f(fx4[2]), fx3 = bf2f(fx4[3]);
  float fc0 = 0.f, fc1 = 0.f, fc2 = 0.f, fc3 = 0.f;
  for (int q = ofsD[ob + j], e = ofsD[ob + j + 1]; q < e; ++q) {
    const int l = lstD[lb + q];
    const int jr = idr[lb + l], jl = idl[lb + l];
    const u16x4 rv = *(const u16x4*)&ghb[(size_t)(lbase + jr) * NCOLS + 2048 + c];
    const u16x4 lv = *(const u16x4*)&ghb[(size_t)(lbase + jl) * NCOLS + 3072 + c];
    const float4 cc = *(const float4*)&c0[(size_t)(lb + l) * HID + c];
    fc0 += sigmoidf_(fx0 + bf2f(rv[0]) + bf2f(lv[0])) * cc.x;
    fc1 += sigmoidf_(fx1 + bf2f(rv[1]) + bf2f(lv[1])) * cc.y;
    fc2 += sigmoidf_(fx2 + bf2f(rv[2]) + bf2f(lv[2])) * cc.z;
    fc3 += sigmoidf_(fx3 + bf2f(rv[3]) + bf2f(lv[3])) * cc.w;
  }

  const u16x4 vi = *(const u16x4*)&gxb[(size_t)r * NCOLS + c];
  const u16x4 vo = *(const u16x4*)&gxb[(size_t)r * NCOLS + 1024 + c];
  const u16x4 vu = *(const u16x4*)&gxb[(size_t)r * NCOLS + 2048 + c];
  float4 hn, cn;
  {
    const float ig = sigmoidf_(bf2f(vi[0]) + a0), og = sigmoidf_(bf2f(vo[0]));
    cn.x = ig * tanhf(bf2f(vu[0])) + fc0; hn.x = og * tanhf(cn.x);
  }
  {
    const float ig = sigmoidf_(bf2f(vi[1]) + a1), og = sigmoidf_(bf2f(vo[1]));
    cn.y = ig * tanhf(bf2f(vu[1])) + fc1; hn.y = og * tanhf(cn.y);
  }
  {
    const float ig = sigmoidf_(bf2f(vi[2]) + a2), og = sigmoidf_(bf2f(vo[2]));
    cn.z = ig * tanhf(bf2f(vu[2])) + fc2; hn.z = og * tanhf(cn.z);
  }
  {
    const float ig = sigmoidf_(bf2f(vi[3]) + a3), og = sigmoidf_(bf2f(vo[3]));
    cn.w = ig * tanhf(bf2f(vu[3])) + fc3; hn.w = og * tanhf(cn.w);
  }

  if (idd[g] == 0) {
    *(float4*)&hout[(size_t)g * HID + c] = *(const float4*)&h0[(size_t)g * HID + c];
    *(float4*)&cout[(size_t)g * HID + c] = *(const float4*)&c0[(size_t)g * HID + c];
  }
  const int m = *mcount;
  if (g < m) {
    const int o = sel[g];
    *(float4*)&hout[(size_t)o * HID + c] = hn;
    *(float4*)&cout[(size_t)o * HID + c] = cn;
  }
}

extern "C" void kernel_launch(void* const* d_in, const int* in_sizes, int n_in,
                              void* d_out, int out_size, void* d_ws, size_t ws_size,
                              hipStream_t stream) {
  const float* x      = (const float*)d_in[0];
  const float* h0     = (const float*)d_in[1];
  const float* c0     = (const float*)d_in[2];
  const float* W_ioux = (const float*)d_in[3];
  const float* W_iouh = (const float*)d_in[4];
  const float* b_iouh = (const float*)d_in[5];
  const float* W_fx   = (const float*)d_in[6];
  const float* W_fh   = (const float*)d_in[7];
  const float* b_fh   = (const float*)d_in[8];
  const int* idd      = (const int*)d_in[9];
  const int* idr      = (const int*)d_in[10];
  const int* idl      = (const int*)d_in[11];
  float* hout = (float*)d_out;
  float* cout = hout + (size_t)ROWS * HID;

  // fixed region (~17.3 MB)
  char* ws = (char*)d_ws;
  unsigned short* Wxt  = (unsigned short*)(ws);
  unsigned short* Wht  = (unsigned short*)(ws + 8388608u);
  float*          bh   = (float*)(ws + 16777216u);
  int*            sel  = (int*)(ws + 16793600u);
  int*            mcnt = (int*)(ws + 16859136u);
  int*            ofsD = (int*)(ws + 16859392u);
  int*            ofsR = (int*)(ws + 16925184u);
  int*            ofsL = (int*)(ws + 16990976u);
  int*            lstD = (int*)(ws + 17056768u);
  int*            lstR = (int*)(ws + 17122304u);
  int*            lstL = (int*)(ws + 17187840u);
  const size_t    base = 17253376u;

  // chunk size: largest power-of-two divisor of 32 fitting ws (10 MiB per batch)
  int C = 32;
  while (C > 1 && base + 10485760ull * (size_t)C > ws_size) C >>= 1;
  const int R = 512 * C;

  char* p = ws + base;
  unsigned short* xb  = (unsigned short*)p;  p += 1048576ull * C;
  unsigned short* hb  = (unsigned short*)p;  p += 1048576ull * C;
  unsigned short* gxb = (unsigned short*)p;  p += 4194304ull * C;
  unsigned short* ghb = (unsigned short*)p;

  prep_all<<<8229, 1024, 0, stream>>>(W_ioux, W_fx, W_iouh, W_fh, b_iouh, b_fh,
                                      idd, idr, idl, Wxt, Wht, bh, sel, mcnt,
                                      ofsD, ofsR, ofsL, lstD, lstR, lstL);

  for (int b0 = 0; b0 < 32; b0 += C) {
    const size_t r0 = (size_t)b0 * 512;
    convert_bf16<<<R, 256, 0, stream>>>(x + r0 * HID, h0 + r0 * HID, xb, hb);
    gemm8<<<dim3(NCOLS / BN, R / BM, 2), 512, 0, stream>>>(xb, hb, Wxt, Wht, gxb, ghb, bh);
    fused_final<<<R, 256, 0, stream>>>(gxb, ghb, h0, c0, idd, idr, idl,
                                       ofsR, lstR, ofsL, lstL, ofsD, lstD,
                                       sel, mcnt, hout, cout, (int)r0);
  }
}

// Round 18
// 476.175 us; speedup vs baseline: 1.4552x; 1.0688x over previous
//
#include <hip/hip_runtime.h>

// NaryTreeLSTMCell: B=32, L=512, E=H=1024.  Outputs h_out, c_out (f32, 2x16384x1024).
//
//   gx = x @ [W_ioux | W_fx]; gh = h0 @ [Wiouh0[:,:H]|Wiouh1[:,:H]|Wfh0+Wfh1|Wfh2+Wfh3]+b
//   add/fc via per-batch CSR gathers; gates -> c_new,h_new; compaction via sel[].
//
// r17: 509us total; accounting closed: gemm 298 (plateau) + fused ~105 (BW-
// bound) + convert ~40 (BW-bound) + prep ~15 + node boundaries. This round:
// merge convert_bf16 INTO prep_all (4096 extra blocks) -> 3-dispatch pipeline
// (prep+convert, gemm, fused). Fallback: per-chunk convert when ws forces C<32.

#define ROWS 16384
#define HID  1024
#define KDIM 1024
#define NCOLS 4096
#define BM 256
#define BN 256

typedef __attribute__((ext_vector_type(4))) int            i32x4;
typedef __attribute__((ext_vector_type(4))) float          f32x4;
typedef __attribute__((ext_vector_type(4))) unsigned short u16x4;
typedef __attribute__((ext_vector_type(8))) unsigned short u16x8;

__device__ __forceinline__ unsigned short f2bf(float f) {
  unsigned u = __float_as_uint(f);
  unsigned r = 0x7FFFu + ((u >> 16) & 1u);
  return (unsigned short)((u + r) >> 16);
}
__device__ __forceinline__ float bf2f(unsigned short v) {
  return __uint_as_float(((unsigned)v) << 16);
}
__device__ __forceinline__ float sigmoidf_(float x) {
  return 1.0f / (1.0f + __expf(-x));
}
__device__ __forceinline__ void gload16(const void* g, void* l) {
  __builtin_amdgcn_global_load_lds(
      (const __attribute__((address_space(1))) void*)g,
      (__attribute__((address_space(3))) void*)l, 16, 0, 0);
}
__device__ __forceinline__ void mfma_bf16(f32x4& acc, i32x4 a, i32x4 b) {
  asm volatile("v_mfma_f32_16x16x32_bf16 %0, %1, %2, %0"
               : "+v"(acc) : "v"(a), "v"(b));
}

// ---- ONE prep dispatch: weight packs + bias + mask scan + CSR + convert ----
// blocks [0,4096): pack Wxt; [4096,8192): pack Wht; [8192,8196): bias;
// 8196: scan_mask; [8197,8229): build_csr; [8229,8229+4096): x/h0 -> bf16
// (only when doConv; otherwise grid stops at 8229).
__global__ __launch_bounds__(1024)
void prep_all(const float* __restrict__ Wioux, const float* __restrict__ Wfx,
              const float* __restrict__ Wiouh, const float* __restrict__ Wfh,
              const float* __restrict__ b_iouh, const float* __restrict__ b_fh,
              const int* __restrict__ idd, const int* __restrict__ idr,
              const int* __restrict__ idl,
              unsigned short* __restrict__ Wxt, unsigned short* __restrict__ Wht,
              float* __restrict__ bh, int* __restrict__ sel, int* __restrict__ mcnt,
              int* __restrict__ ofsD, int* __restrict__ ofsR, int* __restrict__ ofsL,
              int* __restrict__ lstD, int* __restrict__ lstR, int* __restrict__ lstL,
              const float* __restrict__ x, const float* __restrict__ h0,
              unsigned short* __restrict__ xb, unsigned short* __restrict__ hb) {
  __shared__ float tt[32][33];
  __shared__ int ps[1024];
  __shared__ int sidx[512];
  __shared__ int scn[512];
  const int blk = blockIdx.x, t = threadIdx.x;

  if (blk < 4096) {              // ---- pack Wxt ----
    const int n0 = (blk & 127) * 32, k0 = (blk >> 7) * 32;
    const int tx = t & 31, ty = t >> 5;
    const int n = n0 + tx, k = k0 + ty;
    tt[ty][tx] = (n < 3072) ? Wioux[(size_t)k * 3072 + n]
                            : Wfx[(size_t)k * 1024 + (n - 3072)];
    __syncthreads();
    Wxt[(size_t)(n0 + ty) * KDIM + (k0 + tx)] = f2bf(tt[tx][ty]);
  } else if (blk < 8192) {       // ---- pack Wht ----
    const int bb = blk - 4096;
    const int n0 = (bb & 127) * 32, k0 = (bb >> 7) * 32;
    const int tx = t & 31, ty = t >> 5;
    const int n = n0 + tx, k = k0 + ty;
    float v;
    if (n < 1024)      v = Wiouh[(size_t)k * 3072 + n];
    else if (n < 2048) v = Wiouh[3145728u + (size_t)k * 3072 + (n - 1024)];
    else if (n < 3072) { const int c = n - 2048;
      v = Wfh[(size_t)k * 1024 + c] + Wfh[1048576u + (size_t)k * 1024 + c]; }
    else { const int c = n - 3072;
      v = Wfh[2097152u + (size_t)k * 1024 + c] + Wfh[3145728u + (size_t)k * 1024 + c]; }
    tt[ty][tx] = v;
    __syncthreads();
    Wht[(size_t)(n0 + ty) * KDIM + (k0 + tx)] = f2bf(tt[tx][ty]);
  } else if (blk < 8196) {       // ---- bias ----
    const int n = (blk - 8192) * 1024 + t;
    float v;
    if (n < 1024)      v = b_iouh[n];
    else if (n < 2048) v = b_iouh[3072 + (n - 1024)];
    else if (n < 3072) { const int c = n - 2048; v = b_fh[c] + b_fh[1024 + c]; }
    else { const int c = n - 3072; v = b_fh[2048 + c] + b_fh[3072 + c]; }
    bh[n] = v;
  } else if (blk == 8196) {      // ---- global mask compaction scan ----
    int loc[16];
    int cnt = 0;
#pragma unroll
    for (int i = 0; i < 16; ++i) {
      const int v = (idd[t * 16 + i] != 0) ? 1 : 0;
      loc[i] = v; cnt += v;
    }
    ps[t] = cnt;
    __syncthreads();
    for (int off = 1; off < 1024; off <<= 1) {
      const int add = (t >= off) ? ps[t - off] : 0;
      __syncthreads();
      ps[t] += add;
      __syncthreads();
    }
    int rank = (t == 0) ? 0 : ps[t - 1];
#pragma unroll
    for (int i = 0; i < 16; ++i)
      if (loc[i]) sel[rank++] = t * 16 + i;
    if (t == 1023) *mcnt = ps[1023];
  } else if (blk < 8229) {       // ---- per-batch CSR (t<512 active) ----
    const int b = blk - 8197;
    const int gb = b << 9;
    const bool act = (t < 512);
    const int* const srcs[3] = { idd, idr, idl };
    int* const ofss[3] = { ofsD, ofsR, ofsL };
    int* const lsts[3] = { lstD, lstR, lstL };
    for (int a = 0; a < 3; ++a) {
      if (act) { sidx[t] = srcs[a][gb + t]; scn[t] = 0; }
      __syncthreads();
      if (act) atomicAdd(&scn[sidx[t]], 1);
      __syncthreads();
      const int v = act ? scn[t] : 0;
      for (int off = 1; off < 512; off <<= 1) {
        const int add = (act && t >= off) ? scn[t - off] : 0;
        __syncthreads();
        if (act) scn[t] += add;
        __syncthreads();
      }
      if (act) {
        const int start = scn[t] - v;
        ofss[a][b * 513 + t] = start;
        if (t == 511) ofss[a][b * 513 + 512] = scn[511];
        int pos = start;
        for (int l = 0; l < 512; ++l)
          if (sidx[l] == t) lsts[a][gb + (pos++)] = l;
      }
      __syncthreads();
    }
  } else {                       // ---- convert x/h0 -> bf16 (full arrays) ----
    const size_t i = (((size_t)(blk - 8229) * 1024) + t) * 4;
    const float4 a = *(const float4*)&x[i];
    const float4 b = *(const float4*)&h0[i];
    u16x4 av = { f2bf(a.x), f2bf(a.y), f2bf(a.z), f2bf(a.w) };
    u16x4 bv = { f2bf(b.x), f2bf(b.y), f2bf(b.z), f2bf(b.w) };
    *(u16x4*)&xb[i] = av;
    *(u16x4*)&hb[i] = bv;
  }
}

// fallback converter for chunked mode (ws too small for full buffers)
__global__ void convert_bf16(const float* __restrict__ x, const float* __restrict__ h0,
                             unsigned short* __restrict__ xb, unsigned short* __restrict__ hb) {
  const size_t i = ((size_t)blockIdx.x * 256 + threadIdx.x) * 4;
  const float4 a = *(const float4*)&x[i];
  const float4 b = *(const float4*)&h0[i];
  u16x4 av = { f2bf(a.x), f2bf(a.y), f2bf(a.z), f2bf(a.w) };
  u16x4 bv = { f2bf(b.x), f2bf(b.y), f2bf(b.z), f2bf(b.w) };
  *(u16x4*)&xb[i] = av;
  *(u16x4*)&hb[i] = bv;
}

// stage8: one gload16 per wave = 8 rows x 64B. Global seg pre-swizzled ^(row&7);
// LDS stays linear (global_load_lds constraint). rowbase multiple of 8.
__device__ __forceinline__ void stage8(const unsigned short* __restrict__ gp,
                                       unsigned short* __restrict__ lp,
                                       int rowbase, int gbase, int k0, int lane) {
  const int lrow = rowbase + (lane >> 3);
  const int sseg = (lane & 7) ^ ((lane >> 3) & 7);
  gload16(gp + (size_t)(gbase + lrow) * KDIM + k0 + sseg * 8,
          lp + ((size_t)rowbase << 6));
}

#define RD_A(dst, qm)                                                          \
  _Pragma("unroll")                                                            \
  for (int i = 0; i < 4; ++i) {                                                \
    const int row = wr * 128 + (qm) * 64 + i * 16 + m0;                        \
    _Pragma("unroll")                                                          \
    for (int s = 0; s < 2; ++s)                                                \
      dst[i][s] = *(const i32x4*)(Ab + row * 64 + (((kg + s * 4) ^ sw8) << 3)); \
  }

#define RD_B(dst, qn)                                                          \
  _Pragma("unroll")                                                            \
  for (int j = 0; j < 2; ++j) {                                                \
    const int col = wc * 64 + (qn) * 32 + j * 16 + m0;                         \
    _Pragma("unroll")                                                          \
    for (int s = 0; s < 2; ++s)                                                \
      dst[j][s] = *(const i32x4*)(Bb + col * 64 + (((kg + s * 4) ^ sw8) << 3)); \
  }

#define MM(afx, qmb, qnb)                                                      \
  __builtin_amdgcn_s_setprio(1);                                               \
  _Pragma("unroll")                                                            \
  for (int i = 0; i < 4; ++i)                                                  \
    _Pragma("unroll")                                                          \
    for (int j = 0; j < 2; ++j) {                                              \
      mfma_bf16(acc[(qmb) + i][(qnb) + j], afx[i][0], bfr[j][0]);              \
      mfma_bf16(acc[(qmb) + i][(qnb) + j], afx[i][1], bfr[j][1]);              \
    }                                                                          \
  __builtin_amdgcn_s_setprio(0);

__global__ __launch_bounds__(512, 2)
void gemm8(const unsigned short* __restrict__ xb, const unsigned short* __restrict__ hb,
           const unsigned short* __restrict__ Wxt, const unsigned short* __restrict__ Wht,
           unsigned short* __restrict__ gxb, unsigned short* __restrict__ ghb,
           const float* __restrict__ bhv) {
  __shared__ __align__(16) unsigned short S[2][2][256][64];  // [buf][A|B][row][64]

  const unsigned short* A;
  const unsigned short* Bt;
  unsigned short* Cp;
  const float* bias;
  if (blockIdx.z == 0) { A = xb; Bt = Wxt; Cp = gxb; bias = nullptr; }
  else                 { A = hb; Bt = Wht; Cp = ghb; bias = bhv; }

  // T1 XCD-aware swizzle (bijective; ny multiple of 8), y-major within chunk.
  int bx = blockIdx.x, by = blockIdx.y;
  const int ny = gridDim.y;
  if ((ny & 7) == 0) {
    const int n = blockIdx.x + 16 * blockIdx.y;
    const int xcd = n & 7, idx = n >> 3;
    const int ych = ny >> 3;
    bx = idx / ych;
    by = xcd * ych + (idx % ych);
  }
  const int bm = by * BM, bn = bx * BN;

  const int tid = threadIdx.x, w = tid >> 6, lane = tid & 63;
  const int wr = w >> 2, wc = w & 3;
  const int m0 = lane & 15, kg = lane >> 4, sw8 = m0 & 7;
  const int bq0 = ((w >> 1) << 6) + ((w & 1) << 4);

  f32x4 acc[8][4] = {};

  // prologue: stage all of tile 0 into buf 0, drain once
  stage8(A,  &S[0][0][0][0], w * 8,        bm, 0, lane);
  stage8(A,  &S[0][0][0][0], 128 + w * 8,  bm, 0, lane);
  stage8(A,  &S[0][0][0][0], 64 + w * 8,   bm, 0, lane);
  stage8(A,  &S[0][0][0][0], 192 + w * 8,  bm, 0, lane);
  stage8(Bt, &S[0][1][0][0], bq0,          bn, 0, lane);
  stage8(Bt, &S[0][1][0][0], bq0 + 8,      bn, 0, lane);
  stage8(Bt, &S[0][1][0][0], bq0 + 32,     bn, 0, lane);
  stage8(Bt, &S[0][1][0][0], bq0 + 40,     bn, 0, lane);
  asm volatile("s_waitcnt vmcnt(0)" ::: "memory");
  __builtin_amdgcn_s_barrier();

  for (int t = 0; t < 16; ++t) {
    const int cur = t & 1, nxt = cur ^ 1;
    const unsigned short* Ab = &S[cur][0][0][0];
    const unsigned short* Bb = &S[cur][1][0][0];
    unsigned short* An = &S[nxt][0][0][0];
    unsigned short* Bn = &S[nxt][1][0][0];
    const int k1 = (t + 1) << 6;
    const bool st = (t < 15);
    i32x4 af0[4][2], af1[4][2], bfr[2][2];

    // ---- P0 (qm0,qn0): rd af0+bfr0; stage A0(t+1); retire A1(t) ----
    RD_A(af0, 0)
    RD_B(bfr, 0)
    if (st) { stage8(A, An, w * 8, bm, k1, lane);
              stage8(A, An, 128 + w * 8, bm, k1, lane);
              asm volatile("s_waitcnt vmcnt(4)" ::: "memory"); }
    else    { asm volatile("s_waitcnt vmcnt(2)" ::: "memory"); }
    __builtin_amdgcn_s_barrier();
    MM(af0, 0, 0)
    __builtin_amdgcn_s_barrier();

    // ---- P1 (qm1,qn0): rd af1; stage B0(t+1); retire B1(t) ----
    RD_A(af1, 1)
    if (st) { stage8(Bt, Bn, bq0, bn, k1, lane);
              stage8(Bt, Bn, bq0 + 8, bn, k1, lane);
              asm volatile("s_waitcnt vmcnt(4)" ::: "memory"); }
    else    { asm volatile("s_waitcnt vmcnt(0)" ::: "memory"); }
    __builtin_amdgcn_s_barrier();
    MM(af1, 4, 0)
    __builtin_amdgcn_s_barrier();

    // ---- P2 (qm1,qn1): rd bfr1; stage A1(t+1); no wait ----
    RD_B(bfr, 1)
    if (st) { stage8(A, An, 64 + w * 8, bm, k1, lane);
              stage8(A, An, 192 + w * 8, bm, k1, lane); }
    __builtin_amdgcn_s_barrier();
    MM(af1, 4, 2)
    __builtin_amdgcn_s_barrier();

    // ---- P3 (qm0,qn1): no reads; stage B1(t+1); retire A0/B0(t+1) ----
    if (st) { stage8(Bt, Bn, bq0 + 32, bn, k1, lane);
              stage8(Bt, Bn, bq0 + 40, bn, k1, lane);
              asm volatile("s_waitcnt vmcnt(4)" ::: "memory"); }
    __builtin_amdgcn_s_barrier();
    MM(af0, 0, 2)
    __builtin_amdgcn_s_barrier();
  }

  // ---- LDS-transposed epilogue (dead 128KiB dbuf == one 256x256 bf16 tile).
  unsigned short* E = &S[0][0][0][0];   // [256][256] ushort view
  const int rg = kg * 4;
#pragma unroll
  for (int mi = 0; mi < 8; ++mi) {
#pragma unroll
    for (int nj = 0; nj < 4; ++nj) {
      const int col = wc * 64 + nj * 16 + m0;
      const float bv = bias ? bias[bn + col] : 0.0f;
      const int rowb = wr * 128 + mi * 16 + rg;
#pragma unroll
      for (int r = 0; r < 4; ++r) {
        const int row = rowb + r;
        E[row * 256 + (col ^ (((row >> 2) & 3) << 4))] = f2bf(acc[mi][nj][r] + bv);
      }
    }
  }
  __syncthreads();
#pragma unroll
  for (int jj = 0; jj < 16; ++jj) {
    const int row = jj * 16 + (tid >> 5);
    const int c0 = (tid & 31) * 8;
    const int cs = c0 ^ (((row >> 2) & 3) << 4);
    const u16x8 v = *(const u16x8*)&E[row * 256 + cs];
    *(u16x8*)&Cp[(size_t)(bm + row) * NCOLS + bn + c0] = v;
  }
}

// ---- fused epilogue: gather-add + f-gate + activations + compaction write ----
__global__ __launch_bounds__(256)
void fused_final(const unsigned short* __restrict__ gxb, const unsigned short* __restrict__ ghb,
                 const float* __restrict__ h0, const float* __restrict__ c0,
                 const int* __restrict__ idd, const int* __restrict__ idr,
                 const int* __restrict__ idl,
                 const int* __restrict__ ofsR, const int* __restrict__ lstR,
                 const int* __restrict__ ofsL, const int* __restrict__ lstL,
                 const int* __restrict__ ofsD, const int* __restrict__ lstD,
                 const int* __restrict__ sel, const int* __restrict__ mcount,
                 float* __restrict__ hout, float* __restrict__ cout, int r0) {
  const int r = blockIdx.x;
  const int g = r0 + r;
  const int j = g & 511;
  const int bb = g >> 9;
  const int lbase = (r >> 9) << 9;
  const int ob = bb * 513;
  const int lb = bb << 9;
  const int c = threadIdx.x << 2;

  float a0 = 0.f, a1 = 0.f, a2 = 0.f, a3 = 0.f;
  for (int q = ofsR[ob + j], e = ofsR[ob + j + 1]; q < e; ++q) {
    const int l = lstR[lb + q];
    const u16x4 v = *(const u16x4*)&ghb[(size_t)(lbase + l) * NCOLS + c];
    a0 += bf2f(v[0]); a1 += bf2f(v[1]); a2 += bf2f(v[2]); a3 += bf2f(v[3]);
  }
  for (int q = ofsL[ob + j], e = ofsL[ob + j + 1]; q < e; ++q) {
    const int l = lstL[lb + q];
    const u16x4 v = *(const u16x4*)&ghb[(size_t)(lbase + l) * NCOLS + 1024 + c];
    a0 += bf2f(v[0]); a1 += bf2f(v[1]); a2 += bf2f(v[2]); a3 += bf2f(v[3]);
  }

  const u16x4 fx4 = *(const u16x4*)&gxb[(size_t)r * NCOLS + 3072 + c];
  const float fx0 = bf2f(fx4[0]), fx1 = bf2f(fx4[1]), fx2 = bf2f(fx4[2]), fx3 = bf2f(fx4[3]);
  float fc0 = 0.f, fc1 = 0.f, fc2 = 0.f, fc3 = 0.f;
  for (int q = ofsD[ob + j], e = ofsD[ob + j + 1]; q < e; ++q) {
    const int l = lstD[lb + q];
    const int jr = idr[lb + l], jl = idl[lb + l];
    const u16x4 rv = *(const u16x4*)&ghb[(size_t)(lbase + jr) * NCOLS + 2048 + c];
    const u16x4 lv = *(const u16x4*)&ghb[(size_t)(lbase + jl) * NCOLS + 3072 + c];
    const float4 cc = *(const float4*)&c0[(size_t)(lb + l) * HID + c];
    fc0 += sigmoidf_(fx0 + bf2f(rv[0]) + bf2f(lv[0])) * cc.x;
    fc1 += sigmoidf_(fx1 + bf2f(rv[1]) + bf2f(lv[1])) * cc.y;
    fc2 += sigmoidf_(fx2 + bf2f(rv[2]) + bf2f(lv[2])) * cc.z;
    fc3 += sigmoidf_(fx3 + bf2f(rv[3]) + bf2f(lv[3])) * cc.w;
  }

  const u16x4 vi = *(const u16x4*)&gxb[(size_t)r * NCOLS + c];
  const u16x4 vo = *(const u16x4*)&gxb[(size_t)r * NCOLS + 1024 + c];
  const u16x4 vu = *(const u16x4*)&gxb[(size_t)r * NCOLS + 2048 + c];
  float4 hn, cn;
  {
    const float ig = sigmoidf_(bf2f(vi[0]) + a0), og = sigmoidf_(bf2f(vo[0]));
    cn.x = ig * tanhf(bf2f(vu[0])) + fc0; hn.x = og * tanhf(cn.x);
  }
  {
    const float ig = sigmoidf_(bf2f(vi[1]) + a1), og = sigmoidf_(bf2f(vo[1]));
    cn.y = ig * tanhf(bf2f(vu[1])) + fc1; hn.y = og * tanhf(cn.y);
  }
  {
    const float ig = sigmoidf_(bf2f(vi[2]) + a2), og = sigmoidf_(bf2f(vo[2]));
    cn.z = ig * tanhf(bf2f(vu[2])) + fc2; hn.z = og * tanhf(cn.z);
  }
  {
    const float ig = sigmoidf_(bf2f(vi[3]) + a3), og = sigmoidf_(bf2f(vo[3]));
    cn.w = ig * tanhf(bf2f(vu[3])) + fc3; hn.w = og * tanhf(cn.w);
  }

  if (idd[g] == 0) {
    *(float4*)&hout[(size_t)g * HID + c] = *(const float4*)&h0[(size_t)g * HID + c];
    *(float4*)&cout[(size_t)g * HID + c] = *(const float4*)&c0[(size_t)g * HID + c];
  }
  const int m = *mcount;
  if (g < m) {
    const int o = sel[g];
    *(float4*)&hout[(size_t)o * HID + c] = hn;
    *(float4*)&cout[(size_t)o * HID + c] = cn;
  }
}

extern "C" void kernel_launch(void* const* d_in, const int* in_sizes, int n_in,
                              void* d_out, int out_size, void* d_ws, size_t ws_size,
                              hipStream_t stream) {
  const float* x      = (const float*)d_in[0];
  const float* h0     = (const float*)d_in[1];
  const float* c0     = (const float*)d_in[2];
  const float* W_ioux = (const float*)d_in[3];
  const float* W_iouh = (const float*)d_in[4];
  const float* b_iouh = (const float*)d_in[5];
  const float* W_fx   = (const float*)d_in[6];
  const float* W_fh   = (const float*)d_in[7];
  const float* b_fh   = (const float*)d_in[8];
  const int* idd      = (const int*)d_in[9];
  const int* idr      = (const int*)d_in[10];
  const int* idl      = (const int*)d_in[11];
  float* hout = (float*)d_out;
  float* cout = hout + (size_t)ROWS * HID;

  // fixed region (~17.3 MB)
  char* ws = (char*)d_ws;
  unsigned short* Wxt  = (unsigned short*)(ws);
  unsigned short* Wht  = (unsigned short*)(ws + 8388608u);
  float*          bh   = (float*)(ws + 16777216u);
  int*            sel  = (int*)(ws + 16793600u);
  int*            mcnt = (int*)(ws + 16859136u);
  int*            ofsD = (int*)(ws + 16859392u);
  int*            ofsR = (int*)(ws + 16925184u);
  int*            ofsL = (int*)(ws + 16990976u);
  int*            lstD = (int*)(ws + 17056768u);
  int*            lstR = (int*)(ws + 17122304u);
  int*            lstL = (int*)(ws + 17187840u);
  const size_t    base = 17253376u;

  // chunk size: largest power-of-two divisor of 32 fitting ws (10 MiB per batch)
  int C = 32;
  while (C > 1 && base + 10485760ull * (size_t)C > ws_size) C >>= 1;
  const int R = 512 * C;

  char* p = ws + base;
  unsigned short* xb  = (unsigned short*)p;  p += 1048576ull * C;
  unsigned short* hb  = (unsigned short*)p;  p += 1048576ull * C;
  unsigned short* gxb = (unsigned short*)p;  p += 4194304ull * C;
  unsigned short* ghb = (unsigned short*)p;

  const bool full = (C == 32);
  prep_all<<<full ? 12325 : 8229, 1024, 0, stream>>>(
      W_ioux, W_fx, W_iouh, W_fh, b_iouh, b_fh,
      idd, idr, idl, Wxt, Wht, bh, sel, mcnt,
      ofsD, ofsR, ofsL, lstD, lstR, lstL,
      x, h0, xb, hb);

  for (int b0 = 0; b0 < 32; b0 += C) {
    const size_t r0 = (size_t)b0 * 512;
    if (!full)
      convert_bf16<<<R, 256, 0, stream>>>(x + r0 * HID, h0 + r0 * HID, xb, hb);
    gemm8<<<dim3(NCOLS / BN, R / BM, 2), 512, 0, stream>>>(xb, hb, Wxt, Wht, gxb, ghb, bh);
    fused_final<<<R, 256, 0, stream>>>(gxb, ghb, h0, c0, idd, idr, idl,
                                       ofsR, lstR, ofsL, lstL, ofsD, lstD,
                                       sel, mcnt, hout, cout, (int)r0);
  }
}

// Round 19
// 475.617 us; speedup vs baseline: 1.4569x; 1.0012x over previous
//
#include <hip/hip_runtime.h>

// NaryTreeLSTMCell: B=32, L=512, E=H=1024.  Outputs h_out, c_out (f32, 2x16384x1024).
//
//   gx = x @ [W_ioux | W_fx]; gh = h0 @ [Wiouh0[:,:H]|Wiouh1[:,:H]|Wfh0+Wfh1|Wfh2+Wfh3]+b
//   add/fc via per-batch CSR gathers; gates -> c_new,h_new; compaction via sel[].
//
// r17: 509us total; accounting closed: gemm 298 (plateau) + fused ~105 (BW-
// bound) + convert ~40 (BW-bound) + prep ~15 + node boundaries. This round:
// merge convert_bf16 INTO prep_all (4096 extra blocks) -> 3-dispatch pipeline
// (prep+convert, gemm, fused). Fallback: per-chunk convert when ws forces C<32.

#define ROWS 16384
#define HID  1024
#define KDIM 1024
#define NCOLS 4096
#define BM 256
#define BN 256

typedef __attribute__((ext_vector_type(4))) int            i32x4;
typedef __attribute__((ext_vector_type(4))) float          f32x4;
typedef __attribute__((ext_vector_type(4))) unsigned short u16x4;
typedef __attribute__((ext_vector_type(8))) unsigned short u16x8;

__device__ __forceinline__ unsigned short f2bf(float f) {
  unsigned u = __float_as_uint(f);
  unsigned r = 0x7FFFu + ((u >> 16) & 1u);
  return (unsigned short)((u + r) >> 16);
}
__device__ __forceinline__ float bf2f(unsigned short v) {
  return __uint_as_float(((unsigned)v) << 16);
}
__device__ __forceinline__ float sigmoidf_(float x) {
  return 1.0f / (1.0f + __expf(-x));
}
__device__ __forceinline__ void gload16(const void* g, void* l) {
  __builtin_amdgcn_global_load_lds(
      (const __attribute__((address_space(1))) void*)g,
      (__attribute__((address_space(3))) void*)l, 16, 0, 0);
}
__device__ __forceinline__ void mfma_bf16(f32x4& acc, i32x4 a, i32x4 b) {
  asm volatile("v_mfma_f32_16x16x32_bf16 %0, %1, %2, %0"
               : "+v"(acc) : "v"(a), "v"(b));
}

// ---- ONE prep dispatch: weight packs + bias + mask scan + CSR + convert ----
// blocks [0,4096): pack Wxt; [4096,8192): pack Wht; [8192,8196): bias;
// 8196: scan_mask; [8197,8229): build_csr; [8229,8229+4096): x/h0 -> bf16
// (only when doConv; otherwise grid stops at 8229).
__global__ __launch_bounds__(1024)
void prep_all(const float* __restrict__ Wioux, const float* __restrict__ Wfx,
              const float* __restrict__ Wiouh, const float* __restrict__ Wfh,
              const float* __restrict__ b_iouh, const float* __restrict__ b_fh,
              const int* __restrict__ idd, const int* __restrict__ idr,
              const int* __restrict__ idl,
              unsigned short* __restrict__ Wxt, unsigned short* __restrict__ Wht,
              float* __restrict__ bh, int* __restrict__ sel, int* __restrict__ mcnt,
              int* __restrict__ ofsD, int* __restrict__ ofsR, int* __restrict__ ofsL,
              int* __restrict__ lstD, int* __restrict__ lstR, int* __restrict__ lstL,
              const float* __restrict__ x, const float* __restrict__ h0,
              unsigned short* __restrict__ xb, unsigned short* __restrict__ hb) {
  __shared__ float tt[32][33];
  __shared__ int ps[1024];
  __shared__ int sidx[512];
  __shared__ int scn[512];
  const int blk = blockIdx.x, t = threadIdx.x;

  if (blk < 4096) {              // ---- pack Wxt ----
    const int n0 = (blk & 127) * 32, k0 = (blk >> 7) * 32;
    const int tx = t & 31, ty = t >> 5;
    const int n = n0 + tx, k = k0 + ty;
    tt[ty][tx] = (n < 3072) ? Wioux[(size_t)k * 3072 + n]
                            : Wfx[(size_t)k * 1024 + (n - 3072)];
    __syncthreads();
    Wxt[(size_t)(n0 + ty) * KDIM + (k0 + tx)] = f2bf(tt[tx][ty]);
  } else if (blk < 8192) {       // ---- pack Wht ----
    const int bb = blk - 4096;
    const int n0 = (bb & 127) * 32, k0 = (bb >> 7) * 32;
    const int tx = t & 31, ty = t >> 5;
    const int n = n0 + tx, k = k0 + ty;
    float v;
    if (n < 1024)      v = Wiouh[(size_t)k * 3072 + n];
    else if (n < 2048) v = Wiouh[3145728u + (size_t)k * 3072 + (n - 1024)];
    else if (n < 3072) { const int c = n - 2048;
      v = Wfh[(size_t)k * 1024 + c] + Wfh[1048576u + (size_t)k * 1024 + c]; }
    else { const int c = n - 3072;
      v = Wfh[2097152u + (size_t)k * 1024 + c] + Wfh[3145728u + (size_t)k * 1024 + c]; }
    tt[ty][tx] = v;
    __syncthreads();
    Wht[(size_t)(n0 + ty) * KDIM + (k0 + tx)] = f2bf(tt[tx][ty]);
  } else if (blk < 8196) {       // ---- bias ----
    const int n = (blk - 8192) * 1024 + t;
    float v;
    if (n < 1024)      v = b_iouh[n];
    else if (n < 2048) v = b_iouh[3072 + (n - 1024)];
    else if (n < 3072) { const int c = n - 2048; v = b_fh[c] + b_fh[1024 + c]; }
    else { const int c = n - 3072; v = b_fh[2048 + c] + b_fh[3072 + c]; }
    bh[n] = v;
  } else if (blk == 8196) {      // ---- global mask compaction scan ----
    int loc[16];
    int cnt = 0;
#pragma unroll
    for (int i = 0; i < 16; ++i) {
      const int v = (idd[t * 16 + i] != 0) ? 1 : 0;
      loc[i] = v; cnt += v;
    }
    ps[t] = cnt;
    __syncthreads();
    for (int off = 1; off < 1024; off <<= 1) {
      const int add = (t >= off) ? ps[t - off] : 0;
      __syncthreads();
      ps[t] += add;
      __syncthreads();
    }
    int rank = (t == 0) ? 0 : ps[t - 1];
#pragma unroll
    for (int i = 0; i < 16; ++i)
      if (loc[i]) sel[rank++] = t * 16 + i;
    if (t == 1023) *mcnt = ps[1023];
  } else if (blk < 8229) {       // ---- per-batch CSR (t<512 active) ----
    const int b = blk - 8197;
    const int gb = b << 9;
    const bool act = (t < 512);
    const int* const srcs[3] = { idd, idr, idl };
    int* const ofss[3] = { ofsD, ofsR, ofsL };
    int* const lsts[3] = { lstD, lstR, lstL };
    for (int a = 0; a < 3; ++a) {
      if (act) { sidx[t] = srcs[a][gb + t]; scn[t] = 0; }
      __syncthreads();
      if (act) atomicAdd(&scn[sidx[t]], 1);
      __syncthreads();
      const int v = act ? scn[t] : 0;
      for (int off = 1; off < 512; off <<= 1) {
        const int add = (act && t >= off) ? scn[t - off] : 0;
        __syncthreads();
        if (act) scn[t] += add;
        __syncthreads();
      }
      if (act) {
        const int start = scn[t] - v;
        ofss[a][b * 513 + t] = start;
        if (t == 511) ofss[a][b * 513 + 512] = scn[511];
        int pos = start;
        for (int l = 0; l < 512; ++l)
          if (sidx[l] == t) lsts[a][gb + (pos++)] = l;
      }
      __syncthreads();
    }
  } else {                       // ---- convert x/h0 -> bf16 (full arrays) ----
    const size_t i = (((size_t)(blk - 8229) * 1024) + t) * 4;
    const float4 a = *(const float4*)&x[i];
    const float4 b = *(const float4*)&h0[i];
    u16x4 av = { f2bf(a.x), f2bf(a.y), f2bf(a.z), f2bf(a.w) };
    u16x4 bv = { f2bf(b.x), f2bf(b.y), f2bf(b.z), f2bf(b.w) };
    *(u16x4*)&xb[i] = av;
    *(u16x4*)&hb[i] = bv;
  }
}

// fallback converter for chunked mode (ws too small for full buffers)
__global__ void convert_bf16(const float* __restrict__ x, const float* __restrict__ h0,
                             unsigned short* __restrict__ xb, unsigned short* __restrict__ hb) {
  const size_t i = ((size_t)blockIdx.x * 256 + threadIdx.x) * 4;
  const float4 a = *(const float4*)&x[i];
  const float4 b = *(const float4*)&h0[i];
  u16x4 av = { f2bf(a.x), f2bf(a.y), f2bf(a.z), f2bf(a.w) };
  u16x4 bv = { f2bf(b.x), f2bf(b.y), f2bf(b.z), f2bf(b.w) };
  *(u16x4*)&xb[i] = av;
  *(u16x4*)&hb[i] = bv;
}

// stage8: one gload16 per wave = 8 rows x 64B. Global seg pre-swizzled ^(row&7);
// LDS stays linear (global_load_lds constraint). rowbase multiple of 8.
__device__ __forceinline__ void stage8(const unsigned short* __restrict__ gp,
                                       unsigned short* __restrict__ lp,
                                       int rowbase, int gbase, int k0, int lane) {
  const int lrow = rowbase + (lane >> 3);
  const int sseg = (lane & 7) ^ ((lane >> 3) & 7);
  gload16(gp + (size_t)(gbase + lrow) * KDIM + k0 + sseg * 8,
          lp + ((size_t)rowbase << 6));
}

#define RD_A(dst, qm)                                                          \
  _Pragma("unroll")                                                            \
  for (int i = 0; i < 4; ++i) {                                                \
    const int row = wr * 128 + (qm) * 64 + i * 16 + m0;                        \
    _Pragma("unroll")                                                          \
    for (int s = 0; s < 2; ++s)                                                \
      dst[i][s] = *(const i32x4*)(Ab + row * 64 + (((kg + s * 4) ^ sw8) << 3)); \
  }

#define RD_B(dst, qn)                                                          \
  _Pragma("unroll")                                                            \
  for (int j = 0; j < 2; ++j) {                                                \
    const int col = wc * 64 + (qn) * 32 + j * 16 + m0;                         \
    _Pragma("unroll")                                                          \
    for (int s = 0; s < 2; ++s)                                                \
      dst[j][s] = *(const i32x4*)(Bb + col * 64 + (((kg + s * 4) ^ sw8) << 3)); \
  }

#define MM(afx, qmb, qnb)                                                      \
  __builtin_amdgcn_s_setprio(1);                                               \
  _Pragma("unroll")                                                            \
  for (int i = 0; i < 4; ++i)                                                  \
    _Pragma("unroll")                                                          \
    for (int j = 0; j < 2; ++j) {                                              \
      mfma_bf16(acc[(qmb) + i][(qnb) + j], afx[i][0], bfr[j][0]);              \
      mfma_bf16(acc[(qmb) + i][(qnb) + j], afx[i][1], bfr[j][1]);              \
    }                                                                          \
  __builtin_amdgcn_s_setprio(0);

__global__ __launch_bounds__(512, 2)
void gemm8(const unsigned short* __restrict__ xb, const unsigned short* __restrict__ hb,
           const unsigned short* __restrict__ Wxt, const unsigned short* __restrict__ Wht,
           unsigned short* __restrict__ gxb, unsigned short* __restrict__ ghb,
           const float* __restrict__ bhv) {
  __shared__ __align__(16) unsigned short S[2][2][256][64];  // [buf][A|B][row][64]

  const unsigned short* A;
  const unsigned short* Bt;
  unsigned short* Cp;
  const float* bias;
  if (blockIdx.z == 0) { A = xb; Bt = Wxt; Cp = gxb; bias = nullptr; }
  else                 { A = hb; Bt = Wht; Cp = ghb; bias = bhv; }

  // T1 XCD-aware swizzle (bijective; ny multiple of 8), y-major within chunk.
  int bx = blockIdx.x, by = blockIdx.y;
  const int ny = gridDim.y;
  if ((ny & 7) == 0) {
    const int n = blockIdx.x + 16 * blockIdx.y;
    const int xcd = n & 7, idx = n >> 3;
    const int ych = ny >> 3;
    bx = idx / ych;
    by = xcd * ych + (idx % ych);
  }
  const int bm = by * BM, bn = bx * BN;

  const int tid = threadIdx.x, w = tid >> 6, lane = tid & 63;
  const int wr = w >> 2, wc = w & 3;
  const int m0 = lane & 15, kg = lane >> 4, sw8 = m0 & 7;
  const int bq0 = ((w >> 1) << 6) + ((w & 1) << 4);

  f32x4 acc[8][4] = {};

  // prologue: stage all of tile 0 into buf 0, drain once
  stage8(A,  &S[0][0][0][0], w * 8,        bm, 0, lane);
  stage8(A,  &S[0][0][0][0], 128 + w * 8,  bm, 0, lane);
  stage8(A,  &S[0][0][0][0], 64 + w * 8,   bm, 0, lane);
  stage8(A,  &S[0][0][0][0], 192 + w * 8,  bm, 0, lane);
  stage8(Bt, &S[0][1][0][0], bq0,          bn, 0, lane);
  stage8(Bt, &S[0][1][0][0], bq0 + 8,      bn, 0, lane);
  stage8(Bt, &S[0][1][0][0], bq0 + 32,     bn, 0, lane);
  stage8(Bt, &S[0][1][0][0], bq0 + 40,     bn, 0, lane);
  asm volatile("s_waitcnt vmcnt(0)" ::: "memory");
  __builtin_amdgcn_s_barrier();

  for (int t = 0; t < 16; ++t) {
    const int cur = t & 1, nxt = cur ^ 1;
    const unsigned short* Ab = &S[cur][0][0][0];
    const unsigned short* Bb = &S[cur][1][0][0];
    unsigned short* An = &S[nxt][0][0][0];
    unsigned short* Bn = &S[nxt][1][0][0];
    const int k1 = (t + 1) << 6;
    const bool st = (t < 15);
    i32x4 af0[4][2], af1[4][2], bfr[2][2];

    // ---- P0 (qm0,qn0): rd af0+bfr0; stage A0(t+1); retire A1(t) ----
    RD_A(af0, 0)
    RD_B(bfr, 0)
    if (st) { stage8(A, An, w * 8, bm, k1, lane);
              stage8(A, An, 128 + w * 8, bm, k1, lane);
              asm volatile("s_waitcnt vmcnt(4)" ::: "memory"); }
    else    { asm volatile("s_waitcnt vmcnt(2)" ::: "memory"); }
    __builtin_amdgcn_s_barrier();
    MM(af0, 0, 0)
    __builtin_amdgcn_s_barrier();

    // ---- P1 (qm1,qn0): rd af1; stage B0(t+1); retire B1(t) ----
    RD_A(af1, 1)
    if (st) { stage8(Bt, Bn, bq0, bn, k1, lane);
              stage8(Bt, Bn, bq0 + 8, bn, k1, lane);
              asm volatile("s_waitcnt vmcnt(4)" ::: "memory"); }
    else    { asm volatile("s_waitcnt vmcnt(0)" ::: "memory"); }
    __builtin_amdgcn_s_barrier();
    MM(af1, 4, 0)
    __builtin_amdgcn_s_barrier();

    // ---- P2 (qm1,qn1): rd bfr1; stage A1(t+1); no wait ----
    RD_B(bfr, 1)
    if (st) { stage8(A, An, 64 + w * 8, bm, k1, lane);
              stage8(A, An, 192 + w * 8, bm, k1, lane); }
    __builtin_amdgcn_s_barrier();
    MM(af1, 4, 2)
    __builtin_amdgcn_s_barrier();

    // ---- P3 (qm0,qn1): no reads; stage B1(t+1); retire A0/B0(t+1) ----
    if (st) { stage8(Bt, Bn, bq0 + 32, bn, k1, lane);
              stage8(Bt, Bn, bq0 + 40, bn, k1, lane);
              asm volatile("s_waitcnt vmcnt(4)" ::: "memory"); }
    __builtin_amdgcn_s_barrier();
    MM(af0, 0, 2)
    __builtin_amdgcn_s_barrier();
  }

  // ---- LDS-transposed epilogue (dead 128KiB dbuf == one 256x256 bf16 tile).
  unsigned short* E = &S[0][0][0][0];   // [256][256] ushort view
  const int rg = kg * 4;
#pragma unroll
  for (int mi = 0; mi < 8; ++mi) {
#pragma unroll
    for (int nj = 0; nj < 4; ++nj) {
      const int col = wc * 64 + nj * 16 + m0;
      const float bv = bias ? bias[bn + col] : 0.0f;
      const int rowb = wr * 128 + mi * 16 + rg;
#pragma unroll
      for (int r = 0; r < 4; ++r) {
        const int row = rowb + r;
        E[row * 256 + (col ^ (((row >> 2) & 3) << 4))] = f2bf(acc[mi][nj][r] + bv);
      }
    }
  }
  __syncthreads();
#pragma unroll
  for (int jj = 0; jj < 16; ++jj) {
    const int row = jj * 16 + (tid >> 5);
    const int c0 = (tid & 31) * 8;
    const int cs = c0 ^ (((row >> 2) & 3) << 4);
    const u16x8 v = *(const u16x8*)&E[row * 256 + cs];
    *(u16x8*)&Cp[(size_t)(bm + row) * NCOLS + bn + c0] = v;
  }
}

// ---- fused epilogue: gather-add + f-gate + activations + compaction write ----
__global__ __launch_bounds__(256)
void fused_final(const unsigned short* __restrict__ gxb, const unsigned short* __restrict__ ghb,
                 const float* __restrict__ h0, const float* __restrict__ c0,
                 const int* __restrict__ idd, const int* __restrict__ idr,
                 const int* __restrict__ idl,
                 const int* __restrict__ ofsR, const int* __restrict__ lstR,
                 const int* __restrict__ ofsL, const int* __restrict__ lstL,
                 const int* __restrict__ ofsD, const int* __restrict__ lstD,
                 const int* __restrict__ sel, const int* __restrict__ mcount,
                 float* __restrict__ hout, float* __restrict__ cout, int r0) {
  const int r = blockIdx.x;
  const int g = r0 + r;
  const int j = g & 511;
  const int bb = g >> 9;
  const int lbase = (r >> 9) << 9;
  const int ob = bb * 513;
  const int lb = bb << 9;
  const int c = threadIdx.x << 2;

  float a0 = 0.f, a1 = 0.f, a2 = 0.f, a3 = 0.f;
  for (int q = ofsR[ob + j], e = ofsR[ob + j + 1]; q < e; ++q) {
    const int l = lstR[lb + q];
    const u16x4 v = *(const u16x4*)&ghb[(size_t)(lbase + l) * NCOLS + c];
    a0 += bf2f(v[0]); a1 += bf2f(v[1]); a2 += bf2f(v[2]); a3 += bf2f(v[3]);
  }
  for (int q = ofsL[ob + j], e = ofsL[ob + j + 1]; q < e; ++q) {
    const int l = lstL[lb + q];
    const u16x4 v = *(const u16x4*)&ghb[(size_t)(lbase + l) * NCOLS + 1024 + c];
    a0 += bf2f(v[0]); a1 += bf2f(v[1]); a2 += bf2f(v[2]); a3 += bf2f(v[3]);
  }

  const u16x4 fx4 = *(const u16x4*)&gxb[(size_t)r * NCOLS + 3072 + c];
  const float fx0 = bf2f(fx4[0]), fx1 = bf2f(fx4[1]), fx2 = bf2f(fx4[2]), fx3 = bf2f(fx4[3]);
  float fc0 = 0.f, fc1 = 0.f, fc2 = 0.f, fc3 = 0.f;
  for (int q = ofsD[ob + j], e = ofsD[ob + j + 1]; q < e; ++q) {
    const int l = lstD[lb + q];
    const int jr = idr[lb + l], jl = idl[lb + l];
    const u16x4 rv = *(const u16x4*)&ghb[(size_t)(lbase + jr) * NCOLS + 2048 + c];
    const u16x4 lv = *(const u16x4*)&ghb[(size_t)(lbase + jl) * NCOLS + 3072 + c];
    const float4 cc = *(const float4*)&c0[(size_t)(lb + l) * HID + c];
    fc0 += sigmoidf_(fx0 + bf2f(rv[0]) + bf2f(lv[0])) * cc.x;
    fc1 += sigmoidf_(fx1 + bf2f(rv[1]) + bf2f(lv[1])) * cc.y;
    fc2 += sigmoidf_(fx2 + bf2f(rv[2]) + bf2f(lv[2])) * cc.z;
    fc3 += sigmoidf_(fx3 + bf2f(rv[3]) + bf2f(lv[3])) * cc.w;
  }

  const u16x4 vi = *(const u16x4*)&gxb[(size_t)r * NCOLS + c];
  const u16x4 vo = *(const u16x4*)&gxb[(size_t)r * NCOLS + 1024 + c];
  const u16x4 vu = *(const u16x4*)&gxb[(size_t)r * NCOLS + 2048 + c];
  float4 hn, cn;
  {
    const float ig = sigmoidf_(bf2f(vi[0]) + a0), og = sigmoidf_(bf2f(vo[0]));
    cn.x = ig * tanhf(bf2f(vu[0])) + fc0; hn.x = og * tanhf(cn.x);
  }
  {
    const float ig = sigmoidf_(bf2f(vi[1]) + a1), og = sigmoidf_(bf2f(vo[1]));
    cn.y = ig * tanhf(bf2f(vu[1])) + fc1; hn.y = og * tanhf(cn.y);
  }
  {
    const float ig = sigmoidf_(bf2f(vi[2]) + a2), og = sigmoidf_(bf2f(vo[2]));
    cn.z = ig * tanhf(bf2f(vu[2])) + fc2; hn.z = og * tanhf(cn.z);
  }
  {
    const float ig = sigmoidf_(bf2f(vi[3]) + a3), og = sigmoidf_(bf2f(vo[3]));
    cn.w = ig * tanhf(bf2f(vu[3])) + fc3; hn.w = og * tanhf(cn.w);
  }

  if (idd[g] == 0) {
    *(float4*)&hout[(size_t)g * HID + c] = *(const float4*)&h0[(size_t)g * HID + c];
    *(float4*)&cout[(size_t)g * HID + c] = *(const float4*)&c0[(size_t)g * HID + c];
  }
  const int m = *mcount;
  if (g < m) {
    const int o = sel[g];
    *(float4*)&hout[(size_t)o * HID + c] = hn;
    *(float4*)&cout[(size_t)o * HID + c] = cn;
  }
}

extern "C" void kernel_launch(void* const* d_in, const int* in_sizes, int n_in,
                              void* d_out, int out_size, void* d_ws, size_t ws_size,
                              hipStream_t stream) {
  const float* x      = (const float*)d_in[0];
  const float* h0     = (const float*)d_in[1];
  const float* c0     = (const float*)d_in[2];
  const float* W_ioux = (const float*)d_in[3];
  const float* W_iouh = (const float*)d_in[4];
  const float* b_iouh = (const float*)d_in[5];
  const float* W_fx   = (const float*)d_in[6];
  const float* W_fh   = (const float*)d_in[7];
  const float* b_fh   = (const float*)d_in[8];
  const int* idd      = (const int*)d_in[9];
  const int* idr      = (const int*)d_in[10];
  const int* idl      = (const int*)d_in[11];
  float* hout = (float*)d_out;
  float* cout = hout + (size_t)ROWS * HID;

  // fixed region (~17.3 MB)
  char* ws = (char*)d_ws;
  unsigned short* Wxt  = (unsigned short*)(ws);
  unsigned short* Wht  = (unsigned short*)(ws + 8388608u);
  float*          bh   = (float*)(ws + 16777216u);
  int*            sel  = (int*)(ws + 16793600u);
  int*            mcnt = (int*)(ws + 16859136u);
  int*            ofsD = (int*)(ws + 16859392u);
  int*            ofsR = (int*)(ws + 16925184u);
  int*            ofsL = (int*)(ws + 16990976u);
  int*            lstD = (int*)(ws + 17056768u);
  int*            lstR = (int*)(ws + 17122304u);
  int*            lstL = (int*)(ws + 17187840u);
  const size_t    base = 17253376u;

  // chunk size: largest power-of-two divisor of 32 fitting ws (10 MiB per batch)
  int C = 32;
  while (C > 1 && base + 10485760ull * (size_t)C > ws_size) C >>= 1;
  const int R = 512 * C;

  char* p = ws + base;
  unsigned short* xb  = (unsigned short*)p;  p += 1048576ull * C;
  unsigned short* hb  = (unsigned short*)p;  p += 1048576ull * C;
  unsigned short* gxb = (unsigned short*)p;  p += 4194304ull * C;
  unsigned short* ghb = (unsigned short*)p;

  const bool full = (C == 32);
  prep_all<<<full ? 12325 : 8229, 1024, 0, stream>>>(
      W_ioux, W_fx, W_iouh, W_fh, b_iouh, b_fh,
      idd, idr, idl, Wxt, Wht, bh, sel, mcnt,
      ofsD, ofsR, ofsL, lstD, lstR, lstL,
      x, h0, xb, hb);

  for (int b0 = 0; b0 < 32; b0 += C) {
    const size_t r0 = (size_t)b0 * 512;
    if (!full)
      convert_bf16<<<R, 256, 0, stream>>>(x + r0 * HID, h0 + r0 * HID, xb, hb);
    gemm8<<<dim3(NCOLS / BN, R / BM, 2), 512, 0, stream>>>(xb, hb, Wxt, Wht, gxb, ghb, bh);
    fused_final<<<R, 256, 0, stream>>>(gxb, ghb, h0, c0, idd, idr, idl,
                                       ofsR, lstR, ofsL, lstL, ofsD, lstD,
                                       sel, mcnt, hout, cout, (int)r0);
  }
}

// Round 20
// 460.461 us; speedup vs baseline: 1.5048x; 1.0329x over previous
//
#include <hip/hip_runtime.h>

// NaryTreeLSTMCell: B=32, L=512, E=H=1024.  Outputs h_out, c_out (f32, 2x16384x1024).
//
//   gx = x @ [W_ioux | W_fx]; gh = h0 @ [Wiouh0[:,:H]|Wiouh1[:,:H]|Wfh0+Wfh1|Wfh2+Wfh3]+b
//   add/fc via per-batch CSR gathers; gates -> c_new,h_new; compaction via sel[].
//
// r19: 476us. r9 ablation: barrier skeleton alone = +88us over MFMA floor
// (128 s_barrier/block). Hazard re-derivation: post-MFMA barriers protect
// NOTHING (MM reads regs; stages write the other buffer; all cross-wave
// stage->read deps are ordered by the pre-MM {vmcnt;barrier} pairs):
//   t+1:P0 reads <- t:P3 vmcnt(4)+bar (A0/B0);  t:P1 reads <- t:P0 (A1);
//   t:P2 reads <- t:P1 (B1);  P2 needs no wait/barrier at all.
// This round: 3 barriers/tile instead of 8 (same 3 counted vmcnt waits).
// Everything else identical to round 19 (prep_all fusion, r7 fused_final).

#define ROWS 16384
#define HID  1024
#define KDIM 1024
#define NCOLS 4096
#define BM 256
#define BN 256

typedef __attribute__((ext_vector_type(4))) int            i32x4;
typedef __attribute__((ext_vector_type(4))) float          f32x4;
typedef __attribute__((ext_vector_type(4))) unsigned short u16x4;
typedef __attribute__((ext_vector_type(8))) unsigned short u16x8;

__device__ __forceinline__ unsigned short f2bf(float f) {
  unsigned u = __float_as_uint(f);
  unsigned r = 0x7FFFu + ((u >> 16) & 1u);
  return (unsigned short)((u + r) >> 16);
}
__device__ __forceinline__ float bf2f(unsigned short v) {
  return __uint_as_float(((unsigned)v) << 16);
}
__device__ __forceinline__ float sigmoidf_(float x) {
  return 1.0f / (1.0f + __expf(-x));
}
__device__ __forceinline__ void gload16(const void* g, void* l) {
  __builtin_amdgcn_global_load_lds(
      (const __attribute__((address_space(1))) void*)g,
      (__attribute__((address_space(3))) void*)l, 16, 0, 0);
}
__device__ __forceinline__ void mfma_bf16(f32x4& acc, i32x4 a, i32x4 b) {
  asm volatile("v_mfma_f32_16x16x32_bf16 %0, %1, %2, %0"
               : "+v"(acc) : "v"(a), "v"(b));
}

// ---- ONE prep dispatch: weight packs + bias + mask scan + CSR + convert ----
__global__ __launch_bounds__(1024)
void prep_all(const float* __restrict__ Wioux, const float* __restrict__ Wfx,
              const float* __restrict__ Wiouh, const float* __restrict__ Wfh,
              const float* __restrict__ b_iouh, const float* __restrict__ b_fh,
              const int* __restrict__ idd, const int* __restrict__ idr,
              const int* __restrict__ idl,
              unsigned short* __restrict__ Wxt, unsigned short* __restrict__ Wht,
              float* __restrict__ bh, int* __restrict__ sel, int* __restrict__ mcnt,
              int* __restrict__ ofsD, int* __restrict__ ofsR, int* __restrict__ ofsL,
              int* __restrict__ lstD, int* __restrict__ lstR, int* __restrict__ lstL,
              const float* __restrict__ x, const float* __restrict__ h0,
              unsigned short* __restrict__ xb, unsigned short* __restrict__ hb) {
  __shared__ float tt[32][33];
  __shared__ int ps[1024];
  __shared__ int sidx[512];
  __shared__ int scn[512];
  const int blk = blockIdx.x, t = threadIdx.x;

  if (blk < 4096) {              // ---- pack Wxt ----
    const int n0 = (blk & 127) * 32, k0 = (blk >> 7) * 32;
    const int tx = t & 31, ty = t >> 5;
    const int n = n0 + tx, k = k0 + ty;
    tt[ty][tx] = (n < 3072) ? Wioux[(size_t)k * 3072 + n]
                            : Wfx[(size_t)k * 1024 + (n - 3072)];
    __syncthreads();
    Wxt[(size_t)(n0 + ty) * KDIM + (k0 + tx)] = f2bf(tt[tx][ty]);
  } else if (blk < 8192) {       // ---- pack Wht ----
    const int bb = blk - 4096;
    const int n0 = (bb & 127) * 32, k0 = (bb >> 7) * 32;
    const int tx = t & 31, ty = t >> 5;
    const int n = n0 + tx, k = k0 + ty;
    float v;
    if (n < 1024)      v = Wiouh[(size_t)k * 3072 + n];
    else if (n < 2048) v = Wiouh[3145728u + (size_t)k * 3072 + (n - 1024)];
    else if (n < 3072) { const int c = n - 2048;
      v = Wfh[(size_t)k * 1024 + c] + Wfh[1048576u + (size_t)k * 1024 + c]; }
    else { const int c = n - 3072;
      v = Wfh[2097152u + (size_t)k * 1024 + c] + Wfh[3145728u + (size_t)k * 1024 + c]; }
    tt[ty][tx] = v;
    __syncthreads();
    Wht[(size_t)(n0 + ty) * KDIM + (k0 + tx)] = f2bf(tt[tx][ty]);
  } else if (blk < 8196) {       // ---- bias ----
    const int n = (blk - 8192) * 1024 + t;
    float v;
    if (n < 1024)      v = b_iouh[n];
    else if (n < 2048) v = b_iouh[3072 + (n - 1024)];
    else if (n < 3072) { const int c = n - 2048; v = b_fh[c] + b_fh[1024 + c]; }
    else { const int c = n - 3072; v = b_fh[2048 + c] + b_fh[3072 + c]; }
    bh[n] = v;
  } else if (blk == 8196) {      // ---- global mask compaction scan ----
    int loc[16];
    int cnt = 0;
#pragma unroll
    for (int i = 0; i < 16; ++i) {
      const int v = (idd[t * 16 + i] != 0) ? 1 : 0;
      loc[i] = v; cnt += v;
    }
    ps[t] = cnt;
    __syncthreads();
    for (int off = 1; off < 1024; off <<= 1) {
      const int add = (t >= off) ? ps[t - off] : 0;
      __syncthreads();
      ps[t] += add;
      __syncthreads();
    }
    int rank = (t == 0) ? 0 : ps[t - 1];
#pragma unroll
    for (int i = 0; i < 16; ++i)
      if (loc[i]) sel[rank++] = t * 16 + i;
    if (t == 1023) *mcnt = ps[1023];
  } else if (blk < 8229) {       // ---- per-batch CSR (t<512 active) ----
    const int b = blk - 8197;
    const int gb = b << 9;
    const bool act = (t < 512);
    const int* const srcs[3] = { idd, idr, idl };
    int* const ofss[3] = { ofsD, ofsR, ofsL };
    int* const lsts[3] = { lstD, lstR, lstL };
    for (int a = 0; a < 3; ++a) {
      if (act) { sidx[t] = srcs[a][gb + t]; scn[t] = 0; }
      __syncthreads();
      if (act) atomicAdd(&scn[sidx[t]], 1);
      __syncthreads();
      const int v = act ? scn[t] : 0;
      for (int off = 1; off < 512; off <<= 1) {
        const int add = (act && t >= off) ? scn[t - off] : 0;
        __syncthreads();
        if (act) scn[t] += add;
        __syncthreads();
      }
      if (act) {
        const int start = scn[t] - v;
        ofss[a][b * 513 + t] = start;
        if (t == 511) ofss[a][b * 513 + 512] = scn[511];
        int pos = start;
        for (int l = 0; l < 512; ++l)
          if (sidx[l] == t) lsts[a][gb + (pos++)] = l;
      }
      __syncthreads();
    }
  } else {                       // ---- convert x/h0 -> bf16 (full arrays) ----
    const size_t i = (((size_t)(blk - 8229) * 1024) + t) * 4;
    const float4 a = *(const float4*)&x[i];
    const float4 b = *(const float4*)&h0[i];
    u16x4 av = { f2bf(a.x), f2bf(a.y), f2bf(a.z), f2bf(a.w) };
    u16x4 bv = { f2bf(b.x), f2bf(b.y), f2bf(b.z), f2bf(b.w) };
    *(u16x4*)&xb[i] = av;
    *(u16x4*)&hb[i] = bv;
  }
}

// fallback converter for chunked mode (ws too small for full buffers)
__global__ void convert_bf16(const float* __restrict__ x, const float* __restrict__ h0,
                             unsigned short* __restrict__ xb, unsigned short* __restrict__ hb) {
  const size_t i = ((size_t)blockIdx.x * 256 + threadIdx.x) * 4;
  const float4 a = *(const float4*)&x[i];
  const float4 b = *(const float4*)&h0[i];
  u16x4 av = { f2bf(a.x), f2bf(a.y), f2bf(a.z), f2bf(a.w) };
  u16x4 bv = { f2bf(b.x), f2bf(b.y), f2bf(b.z), f2bf(b.w) };
  *(u16x4*)&xb[i] = av;
  *(u16x4*)&hb[i] = bv;
}

// stage8: one gload16 per wave = 8 rows x 64B. Global seg pre-swizzled ^(row&7);
// LDS stays linear (global_load_lds constraint). rowbase multiple of 8.
__device__ __forceinline__ void stage8(const unsigned short* __restrict__ gp,
                                       unsigned short* __restrict__ lp,
                                       int rowbase, int gbase, int k0, int lane) {
  const int lrow = rowbase + (lane >> 3);
  const int sseg = (lane & 7) ^ ((lane >> 3) & 7);
  gload16(gp + (size_t)(gbase + lrow) * KDIM + k0 + sseg * 8,
          lp + ((size_t)rowbase << 6));
}

#define RD_A(dst, qm)                                                          \
  _Pragma("unroll")                                                            \
  for (int i = 0; i < 4; ++i) {                                                \
    const int row = wr * 128 + (qm) * 64 + i * 16 + m0;                        \
    _Pragma("unroll")                                                          \
    for (int s = 0; s < 2; ++s)                                                \
      dst[i][s] = *(const i32x4*)(Ab + row * 64 + (((kg + s * 4) ^ sw8) << 3)); \
  }

#define RD_B(dst, qn)                                                          \
  _Pragma("unroll")                                                            \
  for (int j = 0; j < 2; ++j) {                                                \
    const int col = wc * 64 + (qn) * 32 + j * 16 + m0;                         \
    _Pragma("unroll")                                                          \
    for (int s = 0; s < 2; ++s)                                                \
      dst[j][s] = *(const i32x4*)(Bb + col * 64 + (((kg + s * 4) ^ sw8) << 3)); \
  }

#define MM(afx, qmb, qnb)                                                      \
  __builtin_amdgcn_s_setprio(1);                                               \
  _Pragma("unroll")                                                            \
  for (int i = 0; i < 4; ++i)                                                  \
    _Pragma("unroll")                                                          \
    for (int j = 0; j < 2; ++j) {                                              \
      mfma_bf16(acc[(qmb) + i][(qnb) + j], afx[i][0], bfr[j][0]);              \
      mfma_bf16(acc[(qmb) + i][(qnb) + j], afx[i][1], bfr[j][1]);              \
    }                                                                          \
  __builtin_amdgcn_s_setprio(0);

__global__ __launch_bounds__(512, 2)
void gemm8(const unsigned short* __restrict__ xb, const unsigned short* __restrict__ hb,
           const unsigned short* __restrict__ Wxt, const unsigned short* __restrict__ Wht,
           unsigned short* __restrict__ gxb, unsigned short* __restrict__ ghb,
           const float* __restrict__ bhv) {
  __shared__ __align__(16) unsigned short S[2][2][256][64];  // [buf][A|B][row][64]

  const unsigned short* A;
  const unsigned short* Bt;
  unsigned short* Cp;
  const float* bias;
  if (blockIdx.z == 0) { A = xb; Bt = Wxt; Cp = gxb; bias = nullptr; }
  else                 { A = hb; Bt = Wht; Cp = ghb; bias = bhv; }

  // T1 XCD-aware swizzle (bijective; ny multiple of 8), y-major within chunk.
  int bx = blockIdx.x, by = blockIdx.y;
  const int ny = gridDim.y;
  if ((ny & 7) == 0) {
    const int n = blockIdx.x + 16 * blockIdx.y;
    const int xcd = n & 7, idx = n >> 3;
    const int ych = ny >> 3;
    bx = idx / ych;
    by = xcd * ych + (idx % ych);
  }
  const int bm = by * BM, bn = bx * BN;

  const int tid = threadIdx.x, w = tid >> 6, lane = tid & 63;
  const int wr = w >> 2, wc = w & 3;
  const int m0 = lane & 15, kg = lane >> 4, sw8 = m0 & 7;
  const int bq0 = ((w >> 1) << 6) + ((w & 1) << 4);

  f32x4 acc[8][4] = {};

  // prologue: stage all of tile 0 into buf 0, drain once
  stage8(A,  &S[0][0][0][0], w * 8,        bm, 0, lane);
  stage8(A,  &S[0][0][0][0], 128 + w * 8,  bm, 0, lane);
  stage8(A,  &S[0][0][0][0], 64 + w * 8,   bm, 0, lane);
  stage8(A,  &S[0][0][0][0], 192 + w * 8,  bm, 0, lane);
  stage8(Bt, &S[0][1][0][0], bq0,          bn, 0, lane);
  stage8(Bt, &S[0][1][0][0], bq0 + 8,      bn, 0, lane);
  stage8(Bt, &S[0][1][0][0], bq0 + 32,     bn, 0, lane);
  stage8(Bt, &S[0][1][0][0], bq0 + 40,     bn, 0, lane);
  asm volatile("s_waitcnt vmcnt(0)" ::: "memory");
  __builtin_amdgcn_s_barrier();

  for (int t = 0; t < 16; ++t) {
    const int cur = t & 1, nxt = cur ^ 1;
    const unsigned short* Ab = &S[cur][0][0][0];
    const unsigned short* Bb = &S[cur][1][0][0];
    unsigned short* An = &S[nxt][0][0][0];
    unsigned short* Bn = &S[nxt][1][0][0];
    const int k1 = (t + 1) << 6;
    const bool st = (t < 15);
    i32x4 af0[4][2], af1[4][2], bfr[2][2];

    // ---- P0: rd af0+bf0; stage A0(t+1); retire A1(t); barrier; MM ----
    RD_A(af0, 0)
    RD_B(bfr, 0)
    if (st) { stage8(A, An, w * 8, bm, k1, lane);
              stage8(A, An, 128 + w * 8, bm, k1, lane);
              asm volatile("s_waitcnt vmcnt(4)" ::: "memory"); }
    else    { asm volatile("s_waitcnt vmcnt(2)" ::: "memory"); }
    __builtin_amdgcn_s_barrier();
    MM(af0, 0, 0)

    // ---- P1: rd af1; stage B0(t+1); retire B1(t); barrier; MM ----
    RD_A(af1, 1)
    if (st) { stage8(Bt, Bn, bq0, bn, k1, lane);
              stage8(Bt, Bn, bq0 + 8, bn, k1, lane);
              asm volatile("s_waitcnt vmcnt(4)" ::: "memory"); }
    else    { asm volatile("s_waitcnt vmcnt(0)" ::: "memory"); }
    __builtin_amdgcn_s_barrier();
    MM(af1, 4, 0)

    // ---- P2: rd bf1; stage A1(t+1); NO wait, NO barrier; MM ----
    RD_B(bfr, 1)
    if (st) { stage8(A, An, 64 + w * 8, bm, k1, lane);
              stage8(A, An, 192 + w * 8, bm, k1, lane); }
    MM(af1, 4, 2)

    // ---- P3: stage B1(t+1); retire A0/B0(t+1); barrier; MM ----
    if (st) { stage8(Bt, Bn, bq0 + 32, bn, k1, lane);
              stage8(Bt, Bn, bq0 + 40, bn, k1, lane);
              asm volatile("s_waitcnt vmcnt(4)" ::: "memory"); }
    __builtin_amdgcn_s_barrier();
    MM(af0, 0, 2)
  }

  // ---- LDS-transposed epilogue (dead 128KiB dbuf == one 256x256 bf16 tile).
  // Safe without an extra barrier: all ds_reads were consumed before the final
  // P3 barrier rendezvous; remaining MMs read registers only.
  unsigned short* E = &S[0][0][0][0];   // [256][256] ushort view
  const int rg = kg * 4;
#pragma unroll
  for (int mi = 0; mi < 8; ++mi) {
#pragma unroll
    for (int nj = 0; nj < 4; ++nj) {
      const int col = wc * 64 + nj * 16 + m0;
      const float bv = bias ? bias[bn + col] : 0.0f;
      const int rowb = wr * 128 + mi * 16 + rg;
#pragma unroll
      for (int r = 0; r < 4; ++r) {
        const int row = rowb + r;
        E[row * 256 + (col ^ (((row >> 2) & 3) << 4))] = f2bf(acc[mi][nj][r] + bv);
      }
    }
  }
  __syncthreads();
#pragma unroll
  for (int jj = 0; jj < 16; ++jj) {
    const int row = jj * 16 + (tid >> 5);
    const int c0 = (tid & 31) * 8;
    const int cs = c0 ^ (((row >> 2) & 3) << 4);
    const u16x8 v = *(const u16x8*)&E[row * 256 + cs];
    *(u16x8*)&Cp[(size_t)(bm + row) * NCOLS + bn + c0] = v;
  }
}

// ---- fused epilogue: gather-add + f-gate + activations + compaction write ----
__global__ __launch_bounds__(256)
void fused_final(const unsigned short* __restrict__ gxb, const unsigned short* __restrict__ ghb,
                 const float* __restrict__ h0, const float* __restrict__ c0,
                 const int* __restrict__ idd, const int* __restrict__ idr,
                 const int* __restrict__ idl,
                 const int* __restrict__ ofsR, const int* __restrict__ lstR,
                 const int* __restrict__ ofsL, const int* __restrict__ lstL,
                 const int* __restrict__ ofsD, const int* __restrict__ lstD,
                 const int* __restrict__ sel, const int* __restrict__ mcount,
                 float* __restrict__ hout, float* __restrict__ cout, int r0) {
  const int r = blockIdx.x;
  const int g = r0 + r;
  const int j = g & 511;
  const int bb = g >> 9;
  const int lbase = (r >> 9) << 9;
  const int ob = bb * 513;
  const int lb = bb << 9;
  const int c = threadIdx.x << 2;

  float a0 = 0.f, a1 = 0.f, a2 = 0.f, a3 = 0.f;
  for (int q = ofsR[ob + j], e = ofsR[ob + j + 1]; q < e; ++q) {
    const int l = lstR[lb + q];
    const u16x4 v = *(const u16x4*)&ghb[(size_t)(lbase + l) * NCOLS + c];
    a0 += bf2f(v[0]); a1 += bf2f(v[1]); a2 += bf2f(v[2]); a3 += bf2f(v[3]);
  }
  for (int q = ofsL[ob + j], e = ofsL[ob + j + 1]; q < e; ++q) {
    const int l = lstL[lb + q];
    const u16x4 v = *(const u16x4*)&ghb[(size_t)(lbase + l) * NCOLS + 1024 + c];
    a0 += bf2f(v[0]); a1 += bf2f(v[1]); a2 += bf2f(v[2]); a3 += bf2f(v[3]);
  }

  const u16x4 fx4 = *(const u16x4*)&gxb[(size_t)r * NCOLS + 3072 + c];
  const float fx0 = bf2f(fx4[0]), fx1 = bf2f(fx4[1]), fx2 = bf2f(fx4[2]), fx3 = bf2f(fx4[3]);
  float fc0 = 0.f, fc1 = 0.f, fc2 = 0.f, fc3 = 0.f;
  for (int q = ofsD[ob + j], e = ofsD[ob + j + 1]; q < e; ++q) {
    const int l = lstD[lb + q];
    const int jr = idr[lb + l], jl = idl[lb + l];
    const u16x4 rv = *(const u16x4*)&ghb[(size_t)(lbase + jr) * NCOLS + 2048 + c];
    const u16x4 lv = *(const u16x4*)&ghb[(size_t)(lbase + jl) * NCOLS + 3072 + c];
    const float4 cc = *(const float4*)&c0[(size_t)(lb + l) * HID + c];
    fc0 += sigmoidf_(fx0 + bf2f(rv[0]) + bf2f(lv[0])) * cc.x;
    fc1 += sigmoidf_(fx1 + bf2f(rv[1]) + bf2f(lv[1])) * cc.y;
    fc2 += sigmoidf_(fx2 + bf2f(rv[2]) + bf2f(lv[2])) * cc.z;
    fc3 += sigmoidf_(fx3 + bf2f(rv[3]) + bf2f(lv[3])) * cc.w;
  }

  const u16x4 vi = *(const u16x4*)&gxb[(size_t)r * NCOLS + c];
  const u16x4 vo = *(const u16x4*)&gxb[(size_t)r * NCOLS + 1024 + c];
  const u16x4 vu = *(const u16x4*)&gxb[(size_t)r * NCOLS + 2048 + c];
  float4 hn, cn;
  {
    const float ig = sigmoidf_(bf2f(vi[0]) + a0), og = sigmoidf_(bf2f(vo[0]));
    cn.x = ig * tanhf(bf2f(vu[0])) + fc0; hn.x = og * tanhf(cn.x);
  }
  {
    const float ig = sigmoidf_(bf2f(vi[1]) + a1), og = sigmoidf_(bf2f(vo[1]));
    cn.y = ig * tanhf(bf2f(vu[1])) + fc1; hn.y = og * tanhf(cn.y);
  }
  {
    const float ig = sigmoidf_(bf2f(vi[2]) + a2), og = sigmoidf_(bf2f(vo[2]));
    cn.z = ig * tanhf(bf2f(vu[2])) + fc2; hn.z = og * tanhf(cn.z);
  }
  {
    const float ig = sigmoidf_(bf2f(vi[3]) + a3), og = sigmoidf_(bf2f(vo[3]));
    cn.w = ig * tanhf(bf2f(vu[3])) + fc3; hn.w = og * tanhf(cn.w);
  }

  if (idd[g] == 0) {
    *(float4*)&hout[(size_t)g * HID + c] = *(const float4*)&h0[(size_t)g * HID + c];
    *(float4*)&cout[(size_t)g * HID + c] = *(const float4*)&c0[(size_t)g * HID + c];
  }
  const int m = *mcount;
  if (g < m) {
    const int o = sel[g];
    *(float4*)&hout[(size_t)o * HID + c] = hn;
    *(float4*)&cout[(size_t)o * HID + c] = cn;
  }
}

extern "C" void kernel_launch(void* const* d_in, const int* in_sizes, int n_in,
                              void* d_out, int out_size, void* d_ws, size_t ws_size,
                              hipStream_t stream) {
  const float* x      = (const float*)d_in[0];
  const float* h0     = (const float*)d_in[1];
  const float* c0     = (const float*)d_in[2];
  const float* W_ioux = (const float*)d_in[3];
  const float* W_iouh = (const float*)d_in[4];
  const float* b_iouh = (const float*)d_in[5];
  const float* W_fx   = (const float*)d_in[6];
  const float* W_fh   = (const float*)d_in[7];
  const float* b_fh   = (const float*)d_in[8];
  const int* idd      = (const int*)d_in[9];
  const int* idr      = (const int*)d_in[10];
  const int* idl      = (const int*)d_in[11];
  float* hout = (float*)d_out;
  float* cout = hout + (size_t)ROWS * HID;

  // fixed region (~17.3 MB)
  char* ws = (char*)d_ws;
  unsigned short* Wxt  = (unsigned short*)(ws);
  unsigned short* Wht  = (unsigned short*)(ws + 8388608u);
  float*          bh   = (float*)(ws + 16777216u);
  int*            sel  = (int*)(ws + 16793600u);
  int*            mcnt = (int*)(ws + 16859136u);
  int*            ofsD = (int*)(ws + 16859392u);
  int*            ofsR = (int*)(ws + 16925184u);
  int*            ofsL = (int*)(ws + 16990976u);
  int*            lstD = (int*)(ws + 17056768u);
  int*            lstR = (int*)(ws + 17122304u);
  int*            lstL = (int*)(ws + 17187840u);
  const size_t    base = 17253376u;

  // chunk size: largest power-of-two divisor of 32 fitting ws (10 MiB per batch)
  int C = 32;
  while (C > 1 && base + 10485760ull * (size_t)C > ws_size) C >>= 1;
  const int R = 512 * C;

  char* p = ws + base;
  unsigned short* xb  = (unsigned short*)p;  p += 1048576ull * C;
  unsigned short* hb  = (unsigned short*)p;  p += 1048576ull * C;
  unsigned short* gxb = (unsigned short*)p;  p += 4194304ull * C;
  unsigned short* ghb = (unsigned short*)p;

  const bool full = (C == 32);
  prep_all<<<full ? 12325 : 8229, 1024, 0, stream>>>(
      W_ioux, W_fx, W_iouh, W_fh, b_iouh, b_fh,
      idd, idr, idl, Wxt, Wht, bh, sel, mcnt,
      ofsD, ofsR, ofsL, lstD, lstR, lstL,
      x, h0, xb, hb);

  for (int b0 = 0; b0 < 32; b0 += C) {
    const size_t r0 = (size_t)b0 * 512;
    if (!full)
      convert_bf16<<<R, 256, 0, stream>>>(x + r0 * HID, h0 + r0 * HID, xb, hb);
    gemm8<<<dim3(NCOLS / BN, R / BM, 2), 512, 0, stream>>>(xb, hb, Wxt, Wht, gxb, ghb, bh);
    fused_final<<<R, 256, 0, stream>>>(gxb, ghb, h0, c0, idd, idr, idl,
                                       ofsR, lstR, ofsL, lstL, ofsD, lstD,
                                       sel, mcnt, hout, cout, (int)r0);
  }
}

// Round 21
// 457.377 us; speedup vs baseline: 1.5150x; 1.0067x over previous
//
#include <hip/hip_runtime.h>

// NaryTreeLSTMCell: B=32, L=512, E=H=1024.  Outputs h_out, c_out (f32, 2x16384x1024).
//
//   gx = x @ [W_ioux | W_fx]; gh = h0 @ [Wiouh0[:,:H]|Wiouh1[:,:H]|Wfh0+Wfh1|Wfh2+Wfh3]+b
//   add/fc via per-batch CSR gathers; gates -> c_new,h_new; compaction via sel[].
//
// r20: 3-barrier/tile K-loop -> gemm 282us (MfmaUtil 43), total 460. Barrier
// cost confirmed (~3us per barrier-per-tile). This round: 2 barriers + 2 waits
// per tile via re-grouped stages: P0:{A0,B0}, P1:{A1}, P2:{B1}, P3:none.
//   t:P0 {vmcnt(4); bar}: retires+publishes A1(t),B1(t) for P1/P2 reads
//   t:P3 {vmcnt(4); bar}: retires+publishes A0B0(t+1) for t+1:P0 reads
// Flights >= 2 phases everywhere (same minimums as r20). Tail: t=15:P0
// vmcnt(0); post-loop barrier protects epilogue LDS reuse.

#define ROWS 16384
#define HID  1024
#define KDIM 1024
#define NCOLS 4096
#define BM 256
#define BN 256

typedef __attribute__((ext_vector_type(4))) int            i32x4;
typedef __attribute__((ext_vector_type(4))) float          f32x4;
typedef __attribute__((ext_vector_type(4))) unsigned short u16x4;
typedef __attribute__((ext_vector_type(8))) unsigned short u16x8;

__device__ __forceinline__ unsigned short f2bf(float f) {
  unsigned u = __float_as_uint(f);
  unsigned r = 0x7FFFu + ((u >> 16) & 1u);
  return (unsigned short)((u + r) >> 16);
}
__device__ __forceinline__ float bf2f(unsigned short v) {
  return __uint_as_float(((unsigned)v) << 16);
}
__device__ __forceinline__ float sigmoidf_(float x) {
  return 1.0f / (1.0f + __expf(-x));
}
__device__ __forceinline__ void gload16(const void* g, void* l) {
  __builtin_amdgcn_global_load_lds(
      (const __attribute__((address_space(1))) void*)g,
      (__attribute__((address_space(3))) void*)l, 16, 0, 0);
}
__device__ __forceinline__ void mfma_bf16(f32x4& acc, i32x4 a, i32x4 b) {
  asm volatile("v_mfma_f32_16x16x32_bf16 %0, %1, %2, %0"
               : "+v"(acc) : "v"(a), "v"(b));
}

// ---- ONE prep dispatch: weight packs + bias + mask scan + CSR + convert ----
__global__ __launch_bounds__(1024)
void prep_all(const float* __restrict__ Wioux, const float* __restrict__ Wfx,
              const float* __restrict__ Wiouh, const float* __restrict__ Wfh,
              const float* __restrict__ b_iouh, const float* __restrict__ b_fh,
              const int* __restrict__ idd, const int* __restrict__ idr,
              const int* __restrict__ idl,
              unsigned short* __restrict__ Wxt, unsigned short* __restrict__ Wht,
              float* __restrict__ bh, int* __restrict__ sel, int* __restrict__ mcnt,
              int* __restrict__ ofsD, int* __restrict__ ofsR, int* __restrict__ ofsL,
              int* __restrict__ lstD, int* __restrict__ lstR, int* __restrict__ lstL,
              const float* __restrict__ x, const float* __restrict__ h0,
              unsigned short* __restrict__ xb, unsigned short* __restrict__ hb) {
  __shared__ float tt[32][33];
  __shared__ int ps[1024];
  __shared__ int sidx[512];
  __shared__ int scn[512];
  const int blk = blockIdx.x, t = threadIdx.x;

  if (blk < 4096) {              // ---- pack Wxt ----
    const int n0 = (blk & 127) * 32, k0 = (blk >> 7) * 32;
    const int tx = t & 31, ty = t >> 5;
    const int n = n0 + tx, k = k0 + ty;
    tt[ty][tx] = (n < 3072) ? Wioux[(size_t)k * 3072 + n]
                            : Wfx[(size_t)k * 1024 + (n - 3072)];
    __syncthreads();
    Wxt[(size_t)(n0 + ty) * KDIM + (k0 + tx)] = f2bf(tt[tx][ty]);
  } else if (blk < 8192) {       // ---- pack Wht ----
    const int bb = blk - 4096;
    const int n0 = (bb & 127) * 32, k0 = (bb >> 7) * 32;
    const int tx = t & 31, ty = t >> 5;
    const int n = n0 + tx, k = k0 + ty;
    float v;
    if (n < 1024)      v = Wiouh[(size_t)k * 3072 + n];
    else if (n < 2048) v = Wiouh[3145728u + (size_t)k * 3072 + (n - 1024)];
    else if (n < 3072) { const int c = n - 2048;
      v = Wfh[(size_t)k * 1024 + c] + Wfh[1048576u + (size_t)k * 1024 + c]; }
    else { const int c = n - 3072;
      v = Wfh[2097152u + (size_t)k * 1024 + c] + Wfh[3145728u + (size_t)k * 1024 + c]; }
    tt[ty][tx] = v;
    __syncthreads();
    Wht[(size_t)(n0 + ty) * KDIM + (k0 + tx)] = f2bf(tt[tx][ty]);
  } else if (blk < 8196) {       // ---- bias ----
    const int n = (blk - 8192) * 1024 + t;
    float v;
    if (n < 1024)      v = b_iouh[n];
    else if (n < 2048) v = b_iouh[3072 + (n - 1024)];
    else if (n < 3072) { const int c = n - 2048; v = b_fh[c] + b_fh[1024 + c]; }
    else { const int c = n - 3072; v = b_fh[2048 + c] + b_fh[3072 + c]; }
    bh[n] = v;
  } else if (blk == 8196) {      // ---- global mask compaction scan ----
    int loc[16];
    int cnt = 0;
#pragma unroll
    for (int i = 0; i < 16; ++i) {
      const int v = (idd[t * 16 + i] != 0) ? 1 : 0;
      loc[i] = v; cnt += v;
    }
    ps[t] = cnt;
    __syncthreads();
    for (int off = 1; off < 1024; off <<= 1) {
      const int add = (t >= off) ? ps[t - off] : 0;
      __syncthreads();
      ps[t] += add;
      __syncthreads();
    }
    int rank = (t == 0) ? 0 : ps[t - 1];
#pragma unroll
    for (int i = 0; i < 16; ++i)
      if (loc[i]) sel[rank++] = t * 16 + i;
    if (t == 1023) *mcnt = ps[1023];
  } else if (blk < 8229) {       // ---- per-batch CSR (t<512 active) ----
    const int b = blk - 8197;
    const int gb = b << 9;
    const bool act = (t < 512);
    const int* const srcs[3] = { idd, idr, idl };
    int* const ofss[3] = { ofsD, ofsR, ofsL };
    int* const lsts[3] = { lstD, lstR, lstL };
    for (int a = 0; a < 3; ++a) {
      if (act) { sidx[t] = srcs[a][gb + t]; scn[t] = 0; }
      __syncthreads();
      if (act) atomicAdd(&scn[sidx[t]], 1);
      __syncthreads();
      const int v = act ? scn[t] : 0;
      for (int off = 1; off < 512; off <<= 1) {
        const int add = (act && t >= off) ? scn[t - off] : 0;
        __syncthreads();
        if (act) scn[t] += add;
        __syncthreads();
      }
      if (act) {
        const int start = scn[t] - v;
        ofss[a][b * 513 + t] = start;
        if (t == 511) ofss[a][b * 513 + 512] = scn[511];
        int pos = start;
        for (int l = 0; l < 512; ++l)
          if (sidx[l] == t) lsts[a][gb + (pos++)] = l;
      }
      __syncthreads();
    }
  } else {                       // ---- convert x/h0 -> bf16 (full arrays) ----
    const size_t i = (((size_t)(blk - 8229) * 1024) + t) * 4;
    const float4 a = *(const float4*)&x[i];
    const float4 b = *(const float4*)&h0[i];
    u16x4 av = { f2bf(a.x), f2bf(a.y), f2bf(a.z), f2bf(a.w) };
    u16x4 bv = { f2bf(b.x), f2bf(b.y), f2bf(b.z), f2bf(b.w) };
    *(u16x4*)&xb[i] = av;
    *(u16x4*)&hb[i] = bv;
  }
}

// fallback converter for chunked mode (ws too small for full buffers)
__global__ void convert_bf16(const float* __restrict__ x, const float* __restrict__ h0,
                             unsigned short* __restrict__ xb, unsigned short* __restrict__ hb) {
  const size_t i = ((size_t)blockIdx.x * 256 + threadIdx.x) * 4;
  const float4 a = *(const float4*)&x[i];
  const float4 b = *(const float4*)&h0[i];
  u16x4 av = { f2bf(a.x), f2bf(a.y), f2bf(a.z), f2bf(a.w) };
  u16x4 bv = { f2bf(b.x), f2bf(b.y), f2bf(b.z), f2bf(b.w) };
  *(u16x4*)&xb[i] = av;
  *(u16x4*)&hb[i] = bv;
}

// stage8: one gload16 per wave = 8 rows x 64B. Global seg pre-swizzled ^(row&7);
// LDS stays linear (global_load_lds constraint). rowbase multiple of 8.
__device__ __forceinline__ void stage8(const unsigned short* __restrict__ gp,
                                       unsigned short* __restrict__ lp,
                                       int rowbase, int gbase, int k0, int lane) {
  const int lrow = rowbase + (lane >> 3);
  const int sseg = (lane & 7) ^ ((lane >> 3) & 7);
  gload16(gp + (size_t)(gbase + lrow) * KDIM + k0 + sseg * 8,
          lp + ((size_t)rowbase << 6));
}

#define RD_A(dst, qm)                                                          \
  _Pragma("unroll")                                                            \
  for (int i = 0; i < 4; ++i) {                                                \
    const int row = wr * 128 + (qm) * 64 + i * 16 + m0;                        \
    _Pragma("unroll")                                                          \
    for (int s = 0; s < 2; ++s)                                                \
      dst[i][s] = *(const i32x4*)(Ab + row * 64 + (((kg + s * 4) ^ sw8) << 3)); \
  }

#define RD_B(dst, qn)                                                          \
  _Pragma("unroll")                                                            \
  for (int j = 0; j < 2; ++j) {                                                \
    const int col = wc * 64 + (qn) * 32 + j * 16 + m0;                         \
    _Pragma("unroll")                                                          \
    for (int s = 0; s < 2; ++s)                                                \
      dst[j][s] = *(const i32x4*)(Bb + col * 64 + (((kg + s * 4) ^ sw8) << 3)); \
  }

#define MM(afx, qmb, qnb)                                                      \
  __builtin_amdgcn_s_setprio(1);                                               \
  _Pragma("unroll")                                                            \
  for (int i = 0; i < 4; ++i)                                                  \
    _Pragma("unroll")                                                          \
    for (int j = 0; j < 2; ++j) {                                              \
      mfma_bf16(acc[(qmb) + i][(qnb) + j], afx[i][0], bfr[j][0]);              \
      mfma_bf16(acc[(qmb) + i][(qnb) + j], afx[i][1], bfr[j][1]);              \
    }                                                                          \
  __builtin_amdgcn_s_setprio(0);

__global__ __launch_bounds__(512, 2)
void gemm8(const unsigned short* __restrict__ xb, const unsigned short* __restrict__ hb,
           const unsigned short* __restrict__ Wxt, const unsigned short* __restrict__ Wht,
           unsigned short* __restrict__ gxb, unsigned short* __restrict__ ghb,
           const float* __restrict__ bhv) {
  __shared__ __align__(16) unsigned short S[2][2][256][64];  // [buf][A|B][row][64]

  const unsigned short* A;
  const unsigned short* Bt;
  unsigned short* Cp;
  const float* bias;
  if (blockIdx.z == 0) { A = xb; Bt = Wxt; Cp = gxb; bias = nullptr; }
  else                 { A = hb; Bt = Wht; Cp = ghb; bias = bhv; }

  // T1 XCD-aware swizzle (bijective; ny multiple of 8), y-major within chunk.
  int bx = blockIdx.x, by = blockIdx.y;
  const int ny = gridDim.y;
  if ((ny & 7) == 0) {
    const int n = blockIdx.x + 16 * blockIdx.y;
    const int xcd = n & 7, idx = n >> 3;
    const int ych = ny >> 3;
    bx = idx / ych;
    by = xcd * ych + (idx % ych);
  }
  const int bm = by * BM, bn = bx * BN;

  const int tid = threadIdx.x, w = tid >> 6, lane = tid & 63;
  const int wr = w >> 2, wc = w & 3;
  const int m0 = lane & 15, kg = lane >> 4, sw8 = m0 & 7;
  const int bq0 = ((w >> 1) << 6) + ((w & 1) << 4);

  f32x4 acc[8][4] = {};

  // prologue: stage all of tile 0 into buf 0, drain once
  stage8(A,  &S[0][0][0][0], w * 8,        bm, 0, lane);
  stage8(A,  &S[0][0][0][0], 128 + w * 8,  bm, 0, lane);
  stage8(Bt, &S[0][1][0][0], bq0,          bn, 0, lane);
  stage8(Bt, &S[0][1][0][0], bq0 + 8,      bn, 0, lane);
  stage8(A,  &S[0][0][0][0], 64 + w * 8,   bm, 0, lane);
  stage8(A,  &S[0][0][0][0], 192 + w * 8,  bm, 0, lane);
  stage8(Bt, &S[0][1][0][0], bq0 + 32,     bn, 0, lane);
  stage8(Bt, &S[0][1][0][0], bq0 + 40,     bn, 0, lane);
  asm volatile("s_waitcnt vmcnt(0)" ::: "memory");
  __builtin_amdgcn_s_barrier();

  for (int t = 0; t < 16; ++t) {
    const int cur = t & 1, nxt = cur ^ 1;
    const unsigned short* Ab = &S[cur][0][0][0];
    const unsigned short* Bb = &S[cur][1][0][0];
    unsigned short* An = &S[nxt][0][0][0];
    unsigned short* Bn = &S[nxt][1][0][0];
    const int k1 = (t + 1) << 6;
    const bool st = (t < 15);
    i32x4 af0[4][2], af1[4][2], bfr[2][2];

    // ---- P0: rd af0+bf0; stage A0+B0(t+1); retire A1(t),B1(t); bar; MM ----
    RD_A(af0, 0)
    RD_B(bfr, 0)
    if (st) { stage8(A,  An, w * 8, bm, k1, lane);
              stage8(A,  An, 128 + w * 8, bm, k1, lane);
              stage8(Bt, Bn, bq0, bn, k1, lane);
              stage8(Bt, Bn, bq0 + 8, bn, k1, lane);
              asm volatile("s_waitcnt vmcnt(4)" ::: "memory"); }
    else    { asm volatile("s_waitcnt vmcnt(0)" ::: "memory"); }
    __builtin_amdgcn_s_barrier();
    MM(af0, 0, 0)

    // ---- P1: rd af1 (published by P0 barrier); stage A1(t+1); MM ----
    RD_A(af1, 1)
    if (st) { stage8(A, An, 64 + w * 8, bm, k1, lane);
              stage8(A, An, 192 + w * 8, bm, k1, lane); }
    MM(af1, 4, 0)

    // ---- P2: rd bf1 (published by P0 barrier); stage B1(t+1); MM ----
    RD_B(bfr, 1)
    if (st) { stage8(Bt, Bn, bq0 + 32, bn, k1, lane);
              stage8(Bt, Bn, bq0 + 40, bn, k1, lane); }
    MM(af1, 4, 2)

    // ---- P3: regs only; retire+publish A0B0(t+1); MM ----
    if (st) { asm volatile("s_waitcnt vmcnt(4)" ::: "memory");
              __builtin_amdgcn_s_barrier(); }
    MM(af0, 0, 2)
  }

  // ---- LDS-transposed epilogue (dead 128KiB dbuf == one 256x256 bf16 tile).
  // Barrier: ensure all waves' ds_reads (consumed by their MMs) are done
  // before S is overwritten.
  __builtin_amdgcn_s_barrier();
  unsigned short* E = &S[0][0][0][0];   // [256][256] ushort view
  const int rg = kg * 4;
#pragma unroll
  for (int mi = 0; mi < 8; ++mi) {
#pragma unroll
    for (int nj = 0; nj < 4; ++nj) {
      const int col = wc * 64 + nj * 16 + m0;
      const float bv = bias ? bias[bn + col] : 0.0f;
      const int rowb = wr * 128 + mi * 16 + rg;
#pragma unroll
      for (int r = 0; r < 4; ++r) {
        const int row = rowb + r;
        E[row * 256 + (col ^ (((row >> 2) & 3) << 4))] = f2bf(acc[mi][nj][r] + bv);
      }
    }
  }
  __syncthreads();
#pragma unroll
  for (int jj = 0; jj < 16; ++jj) {
    const int row = jj * 16 + (tid >> 5);
    const int c0 = (tid & 31) * 8;
    const int cs = c0 ^ (((row >> 2) & 3) << 4);
    const u16x8 v = *(const u16x8*)&E[row * 256 + cs];
    *(u16x8*)&Cp[(size_t)(bm + row) * NCOLS + bn + c0] = v;
  }
}

// ---- fused epilogue: gather-add + f-gate + activations + compaction write ----
__global__ __launch_bounds__(256)
void fused_final(const unsigned short* __restrict__ gxb, const unsigned short* __restrict__ ghb,
                 const float* __restrict__ h0, const float* __restrict__ c0,
                 const int* __restrict__ idd, const int* __restrict__ idr,
                 const int* __restrict__ idl,
                 const int* __restrict__ ofsR, const int* __restrict__ lstR,
                 const int* __restrict__ ofsL, const int* __restrict__ lstL,
                 const int* __restrict__ ofsD, const int* __restrict__ lstD,
                 const int* __restrict__ sel, const int* __restrict__ mcount,
                 float* __restrict__ hout, float* __restrict__ cout, int r0) {
  const int r = blockIdx.x;
  const int g = r0 + r;
  const int j = g & 511;
  const int bb = g >> 9;
  const int lbase = (r >> 9) << 9;
  const int ob = bb * 513;
  const int lb = bb << 9;
  const int c = threadIdx.x << 2;

  float a0 = 0.f, a1 = 0.f, a2 = 0.f, a3 = 0.f;
  for (int q = ofsR[ob + j], e = ofsR[ob + j + 1]; q < e; ++q) {
    const int l = lstR[lb + q];
    const u16x4 v = *(const u16x4*)&ghb[(size_t)(lbase + l) * NCOLS + c];
    a0 += bf2f(v[0]); a1 += bf2f(v[1]); a2 += bf2f(v[2]); a3 += bf2f(v[3]);
  }
  for (int q = ofsL[ob + j], e = ofsL[ob + j + 1]; q < e; ++q) {
    const int l = lstL[lb + q];
    const u16x4 v = *(const u16x4*)&ghb[(size_t)(lbase + l) * NCOLS + 1024 + c];
    a0 += bf2f(v[0]); a1 += bf2f(v[1]); a2 += bf2f(v[2]); a3 += bf2f(v[3]);
  }

  const u16x4 fx4 = *(const u16x4*)&gxb[(size_t)r * NCOLS + 3072 + c];
  const float fx0 = bf2f(fx4[0]), fx1 = bf2f(fx4[1]), fx2 = bf2f(fx4[2]), fx3 = bf2f(fx4[3]);
  float fc0 = 0.f, fc1 = 0.f, fc2 = 0.f, fc3 = 0.f;
  for (int q = ofsD[ob + j], e = ofsD[ob + j + 1]; q < e; ++q) {
    const int l = lstD[lb + q];
    const int jr = idr[lb + l], jl = idl[lb + l];
    const u16x4 rv = *(const u16x4*)&ghb[(size_t)(lbase + jr) * NCOLS + 2048 + c];
    const u16x4 lv = *(const u16x4*)&ghb[(size_t)(lbase + jl) * NCOLS + 3072 + c];
    const float4 cc = *(const float4*)&c0[(size_t)(lb + l) * HID + c];
    fc0 += sigmoidf_(fx0 + bf2f(rv[0]) + bf2f(lv[0])) * cc.x;
    fc1 += sigmoidf_(fx1 + bf2f(rv[1]) + bf2f(lv[1])) * cc.y;
    fc2 += sigmoidf_(fx2 + bf2f(rv[2]) + bf2f(lv[2])) * cc.z;
    fc3 += sigmoidf_(fx3 + bf2f(rv[3]) + bf2f(lv[3])) * cc.w;
  }

  const u16x4 vi = *(const u16x4*)&gxb[(size_t)r * NCOLS + c];
  const u16x4 vo = *(const u16x4*)&gxb[(size_t)r * NCOLS + 1024 + c];
  const u16x4 vu = *(const u16x4*)&gxb[(size_t)r * NCOLS + 2048 + c];
  float4 hn, cn;
  {
    const float ig = sigmoidf_(bf2f(vi[0]) + a0), og = sigmoidf_(bf2f(vo[0]));
    cn.x = ig * tanhf(bf2f(vu[0])) + fc0; hn.x = og * tanhf(cn.x);
  }
  {
    const float ig = sigmoidf_(bf2f(vi[1]) + a1), og = sigmoidf_(bf2f(vo[1]));
    cn.y = ig * tanhf(bf2f(vu[1])) + fc1; hn.y = og * tanhf(cn.y);
  }
  {
    const float ig = sigmoidf_(bf2f(vi[2]) + a2), og = sigmoidf_(bf2f(vo[2]));
    cn.z = ig * tanhf(bf2f(vu[2])) + fc2; hn.z = og * tanhf(cn.z);
  }
  {
    const float ig = sigmoidf_(bf2f(vi[3]) + a3), og = sigmoidf_(bf2f(vo[3]));
    cn.w = ig * tanhf(bf2f(vu[3])) + fc3; hn.w = og * tanhf(cn.w);
  }

  if (idd[g] == 0) {
    *(float4*)&hout[(size_t)g * HID + c] = *(const float4*)&h0[(size_t)g * HID + c];
    *(float4*)&cout[(size_t)g * HID + c] = *(const float4*)&c0[(size_t)g * HID + c];
  }
  const int m = *mcount;
  if (g < m) {
    const int o = sel[g];
    *(float4*)&hout[(size_t)o * HID + c] = hn;
    *(float4*)&cout[(size_t)o * HID + c] = cn;
  }
}

extern "C" void kernel_launch(void* const* d_in, const int* in_sizes, int n_in,
                              void* d_out, int out_size, void* d_ws, size_t ws_size,
                              hipStream_t stream) {
  const float* x      = (const float*)d_in[0];
  const float* h0     = (const float*)d_in[1];
  const float* c0     = (const float*)d_in[2];
  const float* W_ioux = (const float*)d_in[3];
  const float* W_iouh = (const float*)d_in[4];
  const float* b_iouh = (const float*)d_in[5];
  const float* W_fx   = (const float*)d_in[6];
  const float* W_fh   = (const float*)d_in[7];
  const float* b_fh   = (const float*)d_in[8];
  const int* idd      = (const int*)d_in[9];
  const int* idr      = (const int*)d_in[10];
  const int* idl      = (const int*)d_in[11];
  float* hout = (float*)d_out;
  float* cout = hout + (size_t)ROWS * HID;

  // fixed region (~17.3 MB)
  char* ws = (char*)d_ws;
  unsigned short* Wxt  = (unsigned short*)(ws);
  unsigned short* Wht  = (unsigned short*)(ws + 8388608u);
  float*          bh   = (float*)(ws + 16777216u);
  int*            sel  = (int*)(ws + 16793600u);
  int*            mcnt = (int*)(ws + 16859136u);
  int*            ofsD = (int*)(ws + 16859392u);
  int*            ofsR = (int*)(ws + 16925184u);
  int*            ofsL = (int*)(ws + 16990976u);
  int*            lstD = (int*)(ws + 17056768u);
  int*            lstR = (int*)(ws + 17122304u);
  int*            lstL = (int*)(ws + 17187840u);
  const size_t    base = 17253376u;

  // chunk size: largest power-of-two divisor of 32 fitting ws (10 MiB per batch)
  int C = 32;
  while (C > 1 && base + 10485760ull * (size_t)C > ws_size) C >>= 1;
  const int R = 512 * C;

  char* p = ws + base;
  unsigned short* xb  = (unsigned short*)p;  p += 1048576ull * C;
  unsigned short* hb  = (unsigned short*)p;  p += 1048576ull * C;
  unsigned short* gxb = (unsigned short*)p;  p += 4194304ull * C;
  unsigned short* ghb = (unsigned short*)p;

  const bool full = (C == 32);
  prep_all<<<full ? 12325 : 8229, 1024, 0, stream>>>(
      W_ioux, W_fx, W_iouh, W_fh, b_iouh, b_fh,
      idd, idr, idl, Wxt, Wht, bh, sel, mcnt,
      ofsD, ofsR, ofsL, lstD, lstR, lstL,
      x, h0, xb, hb);

  for (int b0 = 0; b0 < 32; b0 += C) {
    const size_t r0 = (size_t)b0 * 512;
    if (!full)
      convert_bf16<<<R, 256, 0, stream>>>(x + r0 * HID, h0 + r0 * HID, xb, hb);
    gemm8<<<dim3(NCOLS / BN, R / BM, 2), 512, 0, stream>>>(xb, hb, Wxt, Wht, gxb, ghb, bh);
    fused_final<<<R, 256, 0, stream>>>(gxb, ghb, h0, c0, idd, idr, idl,
                                       ofsR, lstR, ofsL, lstL, ofsD, lstD,
                                       sel, mcnt, hout, cout, (int)r0);
  }
}